// Round 4
// baseline (10873.248 us; speedup 1.0000x reference)
//
#include <hip/hip_runtime.h>
#include <hip/hip_bf16.h>
#include <math.h>

// Problem constants
#define SL 256
#define BS 64
#define DI 1024
#define HH 512
#define TT 17
#define NR (SL*BS)        // 16384 rows
#define G4 (4*HH)         // 2048 gates
#define C2 (2*HH)         // 1024 channels
#define NBLK 128          // blocks per direction in lstm_flag (4 h-units each)

__device__ __forceinline__ float sigm(float x) { return 1.f / (1.f + expf(-x)); }

typedef float vfloat4 __attribute__((ext_vector_type(4)));

// Coherent (cache-bypassing, agent-visible) accesses — used ONLY for the
// h publish (stores) and flag poll (loads). H consumption goes through the
// normal cached path after an agent-scope acquire fence (buffer_inv):
// first reader per XCD pulls from LLC into L2, the rest hit L2.
__device__ __forceinline__ void coh_load4i(int4& d, const int* p) {
    asm volatile("global_load_dwordx4 %0, %1, off sc0 sc1" : "=v"(d) : "v"(p) : "memory");
}
__device__ __forceinline__ void coh_store4(const float4& d, float* p) {
    vfloat4 t; t.x = d.x; t.y = d.y; t.z = d.z; t.w = d.w;   // ext-vector = direct VGPR quad
    asm volatile("global_store_dwordx4 %0, %1, off sc0 sc1" :: "v"(p), "v"(t) : "memory");
}
__device__ __forceinline__ void wait_vm0() { asm volatile("s_waitcnt vmcnt(0)" ::: "memory"); }

// ---------------------------------------------------------------------------
// Pack w_hh (2048x512) -> wp[128 slices][512 k][24] (cols c=g*4+uu, pad 16..23)
// slice s owns h-units {4s..4s+3}; col c<16: g=c>>2, uu=c&3 -> row g*512+4s+uu
// ---------------------------------------------------------------------------
__global__ __launch_bounds__(256) void pack_whh_v3(const float* __restrict__ whh,
                                                   float* __restrict__ wp)
{
    const int s = blockIdx.x;
    for (int idx = threadIdx.x; idx < 512 * 24; idx += 256) {
        const int k = idx / 24, c = idx % 24;
        float v = 0.f;
        if (c < 16) {
            const int g = c >> 2, uu = c & 3;
            v = whh[(size_t)(g * 512 + 4 * s + uu) * HH + k];
        }
        wp[(size_t)s * 12288 + idx] = v;
    }
}

__global__ __launch_bounds__(512) void init_flags(int* __restrict__ f)
{
    f[blockIdx.x * 512 + threadIdx.x] = 0;   // 128*512 = 2*SL*NBLK ints
}

// ---------------------------------------------------------------------------
// xg GEMM: X(16384x1024) @ W^T(1024x2048) + b1 + b2, written SLICE-MAJOR:
// XG2[((s*SL + t)*BS + b)*16 + c], s = (n&511)>>2, c = (n>>9)*4 + (n&3).
// Single-buffered 16KB LDS: 8 blocks/CU — occupancy hides the load latency
// (round-3 double-buffer cut occupancy to 5 and regressed; reverted).
// ---------------------------------------------------------------------------
__global__ __launch_bounds__(256) void gemm_xg(
    const float* __restrict__ A,    // [16384][1024]
    const float* __restrict__ W,    // [2048][1024]
    const float* __restrict__ b1,
    const float* __restrict__ b2,
    float* __restrict__ C)          // slice-major xg
{
    __shared__ float As[16][128];
    __shared__ float Bs[16][128];
    const int tid = threadIdx.x;
    const int m0 = blockIdx.x * 128;
    const int n0 = blockIdx.y * 128;
    const int tm = tid >> 4;
    const int tn = tid & 15;
    const int lr = tid >> 2;
    const int lc = (tid & 3) * 4;

    float acc[8][8];
    #pragma unroll
    for (int i = 0; i < 8; i++)
        #pragma unroll
        for (int j = 0; j < 8; j++) acc[i][j] = 0.f;

    for (int kt = 0; kt < DI; kt += 16) {
        #pragma unroll
        for (int p = 0; p < 2; p++) {
            float4 v = *(const float4*)(A + (size_t)(m0 + p * 64 + lr) * DI + kt + lc);
            As[lc + 0][p * 64 + lr] = v.x;
            As[lc + 1][p * 64 + lr] = v.y;
            As[lc + 2][p * 64 + lr] = v.z;
            As[lc + 3][p * 64 + lr] = v.w;
            float4 w = *(const float4*)(W + (size_t)(n0 + p * 64 + lr) * DI + kt + lc);
            Bs[lc + 0][p * 64 + lr] = w.x;
            Bs[lc + 1][p * 64 + lr] = w.y;
            Bs[lc + 2][p * 64 + lr] = w.z;
            Bs[lc + 3][p * 64 + lr] = w.w;
        }
        __syncthreads();
        #pragma unroll
        for (int kk = 0; kk < 16; kk++) {
            float4 a0 = *(const float4*)&As[kk][tm * 8];
            float4 a1 = *(const float4*)&As[kk][tm * 8 + 4];
            float4 bv0 = *(const float4*)&Bs[kk][tn * 8];
            float4 bv1 = *(const float4*)&Bs[kk][tn * 8 + 4];
            float a[8] = {a0.x, a0.y, a0.z, a0.w, a1.x, a1.y, a1.z, a1.w};
            float b[8] = {bv0.x, bv0.y, bv0.z, bv0.w, bv1.x, bv1.y, bv1.z, bv1.w};
            #pragma unroll
            for (int i = 0; i < 8; i++)
                #pragma unroll
                for (int j = 0; j < 8; j++)
                    acc[i][j] = fmaf(a[i], b[j], acc[i][j]);
        }
        __syncthreads();
    }
    // epilogue: slice-major scatter (float2 per unit-pair)
    const int g  = n0 >> 9;                    // gate, constant per n-tile
    const int u0 = (n0 & 511) + tn * 8;        // first unit (8-aligned)
    const int s0 = u0 >> 2;                    // first slice
    #pragma unroll
    for (int i = 0; i < 8; i++) {
        const int m = m0 + tm * 8 + i;
        const int mt = m >> 6, mb = m & 63;
        #pragma unroll
        for (int sj = 0; sj < 4; sj++) {
            const int n = n0 + tn * 8 + sj * 2;
            float2 v;
            v.x = acc[i][sj * 2 + 0] + b1[n + 0] + b2[n + 0];
            v.y = acc[i][sj * 2 + 1] + b1[n + 1] + b2[n + 1];
            // units u0+2sj, u0+2sj+1 -> slice s0 + (sj>>1), cols g*4 + 2*(sj&1) ..+1
            *(float2*)(C + ((((size_t)(s0 + (sj >> 1)) * SL + mt) * BS + mb) << 4)
                         + g * 4 + 2 * (sj & 1)) = v;
        }
    }
}

// ---------------------------------------------------------------------------
// Flag-pipelined LSTM. Grid 256 (merged dirs, 1 block/CU) or 128 (one dir).
// Block s owns h-units {4s..4s+3} (16 gate cols). Weights LDS-resident.
// Per step: poll prev flags (32 lanes, uncached int4), ONE agent-scope
// acquire fence (s_waitcnt + buffer_inv: drops stale clean L1/L2 lines,
// keeps dirty), then stage H(t-1) with PLAIN CACHED float4 loads in 4
// chunks (next chunk prefetched during compute). All blocks sit at the
// same barrier, so invs cluster before the load burst: first block per
// XCD pulls H from LLC into L2, the other ~31 hit L2 — vs rounds 0-3
// where every block paid full uncached LLC latency for every line.
// GEMM, shfl k-reduce, skewed LDS cross-wave reduce, gates (c in regs),
// publish h via LDS-repacked coherent dwordx4, release flag.
// ---------------------------------------------------------------------------
__global__ __launch_bounds__(512, 2) void lstm_flag(
    const float* __restrict__ xg_f, const float* __restrict__ xg_b,  // slice-major
    const float* __restrict__ wp_f, const float* __restrict__ wp_b,
    float* __restrict__ Hf, float* __restrict__ Hb,
    int* __restrict__ flag_f, int* __restrict__ flag_b,
    float* __restrict__ out,          // channel-major [C2][NR]
    int dir_base)
{
    __shared__ float w_s[512 * 24];              // 49152 B, persistent
    __shared__ float hs[128 * 68];               // 34816 B, reused per chunk
    __shared__ float g_s[16 * 65];               //  4160 B
    __shared__ float hpub[256];                  //  1024 B
    float* const part = hs;                      // [8][1088] overlay (exact fit)

    const int dir = dir_base + (blockIdx.x >> 7);
    const int s   = blockIdx.x & 127;
    const float* xg  = dir ? xg_b : xg_f;
    const float* wp  = dir ? wp_b : wp_f;
    float* Hbuf      = dir ? Hb : Hf;
    int*   flag      = dir ? flag_b : flag_f;
    const int reverse = dir;
    const int col_off = dir * HH;

    const int tid = threadIdx.x;
    const int ks  = tid >> 4;        // 0..31 k-slice
    const int bt  = (tid >> 1) & 7;  // 0..7 batch tile
    const int ct  = tid & 1;         // 0..1 col tile (8 cols each)
    const int wv  = tid >> 6;        // wave 0..7

    // stage weights once (3072 float4)
    {
        const float4* src = (const float4*)(wp + (size_t)s * 12288);
        float4* dst = (float4*)w_s;
        for (int i = tid; i < 3072; i += 512) dst[i] = src[i];
    }

    const float* xgs = xg + (size_t)s * (SL * 1024);
    float cst = 0.f;                  // c-state: tid<256 owns (b=tid&63, uu=tid>>6)
    float4 r[4];
    float4 acc[8][2];

    for (int step = 0; step < SL; ++step) {
        const int t = reverse ? (SL - 1 - step) : step;
        // coalesced xg load (2 dwords/thread, 4 KB/block/step); thread owns
        // gates {tid, tid+512} where gate = b*16 + c
        const float myxg0 = xgs[t * 1024 + tid];
        const float myxg1 = xgs[t * 1024 + 512 + tid];

        if (step > 0) {
            if (tid < 32) {
                const int* fp = flag + (step - 1) * NBLK + tid * 4;
                int4 f;
                for (;;) {
                    coh_load4i(f, fp);
                    wait_vm0();
                    if (f.x & f.y & f.z & f.w) break;
                    __builtin_amdgcn_s_sleep(1);
                }
                // acquire: invalidate stale clean L1/L2 lines (H parity buf
                // cached 2 steps ago). HW inv is cache-wide — one wave
                // suffices; __syncthreads orders the other waves' loads.
                __builtin_amdgcn_fence(__ATOMIC_ACQUIRE, "agent");
            }
            __syncthreads();   // flags seen + inv done; protects w_s/hs reuse

            const float* hsrc = Hbuf + ((step + 1) & 1) * (512 * 64);
            // prefetch chunk 0: 4 x float4 per thread (32 KB/chunk), CACHED
            #pragma unroll
            for (int i = 0; i < 4; ++i)
                r[i] = *(const float4*)(hsrc + (size_t)(i * 512 + tid) * 4);

            #pragma unroll
            for (int i = 0; i < 8; ++i) {
                acc[i][0] = make_float4(0.f, 0.f, 0.f, 0.f);
                acc[i][1] = make_float4(0.f, 0.f, 0.f, 0.f);
            }

            for (int kc = 0; kc < 4; ++kc) {
                if (kc) __syncthreads();           // prev chunk consumed
                #pragma unroll
                for (int i = 0; i < 4; ++i) {      // compiler inserts waitcnt
                    const int idx = i * 512 + tid;        // float4 index in chunk
                    const int k = idx >> 4, b4 = (idx & 15) * 4;
                    *(float4*)&hs[k * 68 + b4] = r[i];
                }
                __syncthreads();                   // hs ready
                if (kc < 3) {                      // prefetch next chunk during compute
                    const float* base = hsrc + (size_t)(kc + 1) * 8192;
                    #pragma unroll
                    for (int i = 0; i < 4; ++i)
                        r[i] = *(const float4*)(base + (size_t)(i * 512 + tid) * 4);
                }
                #pragma unroll
                for (int j = 0; j < 4; ++j) {
                    const int kk = ks + 32 * j;
                    const int kg = kc * 128 + kk;
                    const float4 w0 = *(const float4*)&w_s[kg * 24 + ct * 8];
                    const float4 w1 = *(const float4*)&w_s[kg * 24 + ct * 8 + 4];
                    const float* hp = &hs[kk * 68 + 8 * bt];
                    const float2 h01 = *(const float2*)(hp + 0);
                    const float2 h23 = *(const float2*)(hp + 2);
                    const float2 h45 = *(const float2*)(hp + 4);
                    const float2 h67 = *(const float2*)(hp + 6);
                    const float hv[8] = {h01.x, h01.y, h23.x, h23.y, h45.x, h45.y, h67.x, h67.y};
                    #pragma unroll
                    for (int i = 0; i < 8; ++i) {
                        acc[i][0].x = fmaf(hv[i], w0.x, acc[i][0].x);
                        acc[i][0].y = fmaf(hv[i], w0.y, acc[i][0].y);
                        acc[i][0].z = fmaf(hv[i], w0.z, acc[i][0].z);
                        acc[i][0].w = fmaf(hv[i], w0.w, acc[i][0].w);
                        acc[i][1].x = fmaf(hv[i], w1.x, acc[i][1].x);
                        acc[i][1].y = fmaf(hv[i], w1.y, acc[i][1].y);
                        acc[i][1].z = fmaf(hv[i], w1.z, acc[i][1].z);
                        acc[i][1].w = fmaf(hv[i], w1.w, acc[i][1].w);
                    }
                }
            }
            // k-reduce within wave (ks bits 4,5 of lane)
            #pragma unroll
            for (int i = 0; i < 8; ++i)
                #pragma unroll
                for (int p = 0; p < 2; ++p) {
                    acc[i][p].x += __shfl_xor(acc[i][p].x, 16);
                    acc[i][p].y += __shfl_xor(acc[i][p].y, 16);
                    acc[i][p].z += __shfl_xor(acc[i][p].z, 16);
                    acc[i][p].w += __shfl_xor(acc[i][p].w, 16);
                    acc[i][p].x += __shfl_xor(acc[i][p].x, 32);
                    acc[i][p].y += __shfl_xor(acc[i][p].y, 32);
                    acc[i][p].z += __shfl_xor(acc[i][p].z, 32);
                    acc[i][p].w += __shfl_xor(acc[i][p].w, 32);
                }
            __syncthreads();                       // hs reads done; part overlays hs
            if ((tid & 63) < 16) {                 // skew bt*8 breaks bank aliasing
                #pragma unroll
                for (int i = 0; i < 8; ++i) {
                    const int base = wv * 1088 + (8 * bt + i) * 16 + ct * 8 + bt * 8;
                    *(float4*)&part[base + 0] = acc[i][0];
                    *(float4*)&part[base + 4] = acc[i][1];
                }
            }
            __syncthreads();
        }

        // cross-wave reduce + xg: thread owns gates {tid, tid+512}; gate = b*16+c
        {
            float v0 = myxg0, v1 = myxg1;
            if (step > 0) {
                const int gA = tid, gB = tid + 512;
                const int iA = gA + 8 * (gA >> 7);
                const int iB = gB + 8 * (gB >> 7);
                #pragma unroll
                for (int w = 0; w < 8; ++w) {
                    v0 += part[w * 1088 + iA];
                    v1 += part[w * 1088 + iB];
                }
            }
            g_s[(tid & 15) * 65 + (tid >> 4)] = v0;
            {
                const int gB = tid + 512;
                g_s[(gB & 15) * 65 + (gB >> 4)] = v1;
            }
        }
        __syncthreads();

        if (tid < 256) {
            const int b = tid & 63, uu = tid >> 6;      // uu 0..3
            const float ig = sigm(g_s[(0  + uu) * 65 + b]);
            const float fg = sigm(g_s[(4  + uu) * 65 + b]);
            const float gg = tanhf(g_s[(8  + uu) * 65 + b]);
            const float og = sigm(g_s[(12 + uu) * 65 + b]);
            cst = fg * cst + ig * gg;
            hpub[tid] = og * tanhf(cst);           // [uu][b]
        }
        __syncthreads();
        if (tid < 16) {                            // coalesced publication (1 KB)
            const float4 v = *(const float4*)&hpub[tid * 16];
            coh_store4(v, Hbuf + (step & 1) * (512 * 64) + s * 256 + tid * 16);
            *(float4*)(out + (size_t)(col_off + 4 * s + (tid >> 2)) * NR
                           + (size_t)t * 64 + (tid & 3) * 16) = v;
        }
        if (wv == 0) wait_vm0();                   // h at coherent point
        __syncthreads();
        if (tid == 0)
            __hip_atomic_store(flag + step * NBLK + s, 1,
                               __ATOMIC_RELEASE, __HIP_MEMORY_SCOPE_AGENT);
    }
}

// ---------------------------------------------------------------------------
// BatchNorm stats over channel-major X2 [C2][NR]: block per channel
// ---------------------------------------------------------------------------
__global__ __launch_bounds__(256) void bn_stats(
    const float* __restrict__ X2, float* __restrict__ mean, float* __restrict__ istd)
{
    const int ch = blockIdx.x, tid = threadIdx.x;
    const float* base = X2 + (size_t)ch * NR;
    __shared__ float red[256];
    float s = 0.f;
    for (int i = tid * 4; i < NR; i += 1024) {
        const float4 v = *(const float4*)(base + i);
        s += v.x + v.y + v.z + v.w;
    }
    red[tid] = s; __syncthreads();
    for (int o = 128; o; o >>= 1) { if (tid < o) red[tid] += red[tid + o]; __syncthreads(); }
    const float mu = red[0] * (1.f / NR);
    __syncthreads();
    float vv = 0.f;
    for (int i = tid * 4; i < NR; i += 1024) {
        const float4 v = *(const float4*)(base + i);
        const float d0 = v.x - mu, d1 = v.y - mu, d2 = v.z - mu, d3 = v.w - mu;
        vv += d0 * d0 + d1 * d1 + d2 * d2 + d3 * d3;
    }
    red[tid] = vv; __syncthreads();
    for (int o = 128; o; o >>= 1) { if (tid < o) red[tid] += red[tid + o]; __syncthreads(); }
    if (tid == 0) { mean[ch] = mu; istd[ch] = rsqrtf(red[0] * (1.f / NR) + 1e-5f); }
}

// ---------------------------------------------------------------------------
// Fold BN into linear
// ---------------------------------------------------------------------------
__global__ void fold_lin(const float* __restrict__ lin_w, const float* __restrict__ lin_b,
                         const float* __restrict__ gamma, const float* __restrict__ beta,
                         const float* __restrict__ mean, const float* __restrict__ istd,
                         float* __restrict__ Wf, float* __restrict__ ct)
{
    const int t = blockIdx.x, tid = threadIdx.x;
    __shared__ float red[256];
    float acc = 0.f;
    for (int cc = tid; cc < C2; cc += 256) {
        const float w = lin_w[t * C2 + cc];
        const float g = gamma[cc] * istd[cc];
        Wf[t * C2 + cc] = w * g;
        acc = fmaf(beta[cc] - mean[cc] * g, w, acc);
    }
    red[tid] = acc; __syncthreads();
    for (int o = 128; o; o >>= 1) { if (tid < o) red[tid] += red[tid + o]; __syncthreads(); }
    if (tid == 0) ct[t] = red[0] + lin_b[t];
}

// ---------------------------------------------------------------------------
// Emission logits from channel-major X2: block per timestep t, lane = batch.
// thread (b = tid&63, p = tid>>6) accumulates channels [p*256, p*256+256).
// ---------------------------------------------------------------------------
__global__ __launch_bounds__(256) void emit_logits(
    const float* __restrict__ X2, const float* __restrict__ Wf,
    const float* __restrict__ ct, float* __restrict__ E)
{
    __shared__ float ps[256 * TT];               // 17408 B partials
    const int t = blockIdx.x;
    const int tid = threadIdx.x;
    const int b = tid & 63, p = tid >> 6;
    const float* xb = X2 + (size_t)t * 64 + b;

    float acc[TT];
    #pragma unroll
    for (int k = 0; k < TT; k++) acc[k] = 0.f;

    for (int c0 = p * 256; c0 < p * 256 + 256; c0 += 4) {
        const float x0 = xb[(size_t)(c0 + 0) * NR];
        const float x1 = xb[(size_t)(c0 + 1) * NR];
        const float x2 = xb[(size_t)(c0 + 2) * NR];
        const float x3 = xb[(size_t)(c0 + 3) * NR];
        #pragma unroll
        for (int k = 0; k < TT; k++) {
            const float4 w = *(const float4*)&Wf[k * C2 + c0];   // wave-uniform
            acc[k] = fmaf(x0, w.x, fmaf(x1, w.y, fmaf(x2, w.z, fmaf(x3, w.w, acc[k]))));
        }
    }
    #pragma unroll
    for (int k = 0; k < TT; k++) ps[tid * TT + k] = acc[k];
    __syncthreads();
    if (tid < 64) {
        float* Er = E + ((size_t)tid * SL + t) * TT;
        #pragma unroll
        for (int k = 0; k < TT; k++) {
            float v = ct[k];
            #pragma unroll
            for (int q = 0; q < 4; q++) v += ps[(q * 64 + tid) * TT + k];
            Er[k] = v;
        }
    }
}

// ---------------------------------------------------------------------------
// CRF log-likelihood per batch element
// ---------------------------------------------------------------------------
__global__ __launch_bounds__(64) void crf_llh(
    const float* __restrict__ E, const int* __restrict__ mask,
    const int* __restrict__ labels, const float* __restrict__ startv,
    const float* __restrict__ endv, const float* __restrict__ trans,
    float* __restrict__ res)
{
    const int b = blockIdx.x, lane = threadIdx.x;
    __shared__ float tr[TT][TT];
    for (int i = lane; i < TT * TT; i += 64) tr[i / TT][i % TT] = trans[i];
    __syncthreads();
    const float* Eb = E + (size_t)b * SL * TT;
    const int j = (lane < TT) ? lane : 0;

    float alpha = -1e30f;
    if (lane < TT) alpha = startv[lane] + Eb[lane];

    float numacc = 0.f; int len = 0;
    for (int t = lane; t < SL; t += 64) {
        const int mt = mask[t * BS + b];
        len += (mt != 0);
        if (t >= 1 && mt) {
            const int yp = labels[(t - 1) * BS + b];
            const int yt = labels[t * BS + b];
            numacc += tr[yp][yt] + Eb[t * TT + yt];
        }
    }
    for (int off = 32; off; off >>= 1) {
        numacc += __shfl_xor(numacc, off);
        len += __shfl_xor(len, off);
    }

    for (int t = 1; t < SL; ++t) {
        const int mt = mask[t * BS + b];
        if (mt) {
            float av[TT];
            #pragma unroll
            for (int i = 0; i < TT; i++) av[i] = __shfl(alpha, i);
            const float e = (lane < TT) ? Eb[t * TT + lane] : 0.f;
            float mx = -1e30f;
            #pragma unroll
            for (int i = 0; i < TT; i++) mx = fmaxf(mx, av[i] + tr[i][j]);
            float ssum = 0.f;
            #pragma unroll
            for (int i = 0; i < TT; i++) ssum += expf(av[i] + tr[i][j] - mx);
            const float nxt = mx + logf(ssum) + e;
            if (lane < TT) alpha = nxt;
        }
    }
    float v = (lane < TT) ? alpha + endv[lane] : -1e30f;
    float mx = v;
    for (int off = 32; off; off >>= 1) mx = fmaxf(mx, __shfl_xor(mx, off));
    float se = (lane < TT) ? expf(v - mx) : 0.f;
    for (int off = 32; off; off >>= 1) se += __shfl_xor(se, off);
    const float Z = mx + logf(se);

    if (lane == 0) {
        const int y0 = labels[b];
        float num = startv[y0] + Eb[y0] + numacc;
        const int last = len - 1;
        const int yl = labels[last * BS + b];
        num += endv[yl];
        res[b] = num - Z;
    }
}

__global__ __launch_bounds__(64) void loss_reduce(const float* __restrict__ res, float* __restrict__ out)
{
    const int lane = threadIdx.x;
    float v = res[lane];
    for (int off = 32; off; off >>= 1) v += __shfl_xor(v, off);
    if (lane == 0) out[0] = -v;
}

// ---------------------------------------------------------------------------
// Viterbi per batch element
// ---------------------------------------------------------------------------
__global__ __launch_bounds__(64) void viterbi(
    const float* __restrict__ E, const int* __restrict__ mask,
    const float* __restrict__ startv, const float* __restrict__ endv,
    const float* __restrict__ trans, float* __restrict__ preds)
{
    const int b = blockIdx.x, lane = threadIdx.x;
    __shared__ float tr[TT][TT];
    __shared__ unsigned char bp[SL][TT];
    for (int i = lane; i < TT * TT; i += 64) tr[i / TT][i % TT] = trans[i];
    __syncthreads();
    const float* Eb = E + (size_t)b * SL * TT;
    const int j = (lane < TT) ? lane : 0;

    float score = (lane < TT) ? startv[lane] + Eb[lane] : -1e30f;
    for (int t = 1; t < SL; ++t) {
        float av[TT];
        #pragma unroll
        for (int i = 0; i < TT; i++) av[i] = __shfl(score, i);
        float best = -1e30f; int bi = 0;
        #pragma unroll
        for (int i = 0; i < TT; i++) {
            const float cand = av[i] + tr[i][j];
            if (cand > best) { best = cand; bi = i; }   // strict > => first max
        }
        const int mt = mask[t * BS + b];
        if (lane < TT) {
            bp[t][lane] = (unsigned char)bi;
            if (mt) score = best + Eb[t * TT + lane];
        }
    }
    float v = (lane < TT) ? score + endv[lane] : -1e30f;
    float mx = v;
    for (int off = 32; off; off >>= 1) mx = fmaxf(mx, __shfl_xor(mx, off));
    unsigned long long ball = __ballot(v == mx);
    const int last_tag = __ffsll(ball) - 1;
    __syncthreads();

    if (lane == 0) {
        int tag = last_tag;
        float* pb = preds + (size_t)b * SL;
        for (int t = SL - 1; t >= 1; --t) {
            const int mt = mask[t * BS + b];
            pb[t] = mt ? (float)tag : 0.f;
            if (mt) tag = bp[t][tag];
        }
        pb[0] = mask[b] ? (float)tag : 0.f;
    }
}

// ---------------------------------------------------------------------------
extern "C" void kernel_launch(void* const* d_in, const int* in_sizes, int n_in,
                              void* d_out, int out_size, void* d_ws, size_t ws_size,
                              hipStream_t stream)
{
    const float* word    = (const float*)d_in[0];
    const int*   mask    = (const int*)  d_in[1];
    const int*   labels  = (const int*)  d_in[2];
    const float* w_ih_f  = (const float*)d_in[3];
    const float* w_hh_f  = (const float*)d_in[4];
    const float* b_ih_f  = (const float*)d_in[5];
    const float* b_hh_f  = (const float*)d_in[6];
    const float* w_ih_b  = (const float*)d_in[7];
    const float* w_hh_b  = (const float*)d_in[8];
    const float* b_ih_b  = (const float*)d_in[9];
    const float* b_hh_b  = (const float*)d_in[10];
    const float* gamma   = (const float*)d_in[11];
    const float* beta    = (const float*)d_in[12];
    const float* lin_w   = (const float*)d_in[13];
    const float* lin_b   = (const float*)d_in[14];
    const float* c_start = (const float*)d_in[15];
    const float* c_end   = (const float*)d_in[16];
    const float* c_trans = (const float*)d_in[17];
    float* out = (float*)d_out;
    (void)in_sizes; (void)n_in; (void)out_size;

    char* ws = (char*)d_ws;
    size_t off = 0;
    auto alloc = [&](size_t bytes) {
        void* p = ws + off;
        off += (bytes + 255) & ~(size_t)255;
        return p;
    };
    float* XG_F  = (float*)alloc((size_t)NR * G4 * 4);          // 128 MB
    float* WPK_F = (float*)alloc((size_t)128 * 12288 * 4);      // 6.3 MB
    float* WPK_B = (float*)alloc((size_t)128 * 12288 * 4);      // 6.3 MB
    float* LOUT  = (float*)alloc((size_t)NR * C2 * 4);          // 64 MB channel-major
    float* HB_F  = (float*)alloc((size_t)2 * 512 * 64 * 4);     // 256 KB
    float* HB_B  = (float*)alloc((size_t)2 * 512 * 64 * 4);     // 256 KB
    int*   FLAGS = (int*)  alloc((size_t)2 * SL * NBLK * 4);    // 256 KB
    float* MEAN  = (float*)alloc(C2 * 4);
    float* ISTD  = (float*)alloc(C2 * 4);
    float* WF    = (float*)alloc(TT * C2 * 4);
    float* CT    = (float*)alloc(TT * 4);
    float* Ebuf  = (float*)alloc((size_t)BS * SL * TT * 4);
    float* RES   = (float*)alloc(BS * 4);
    float* XG_B  = (float*)alloc((size_t)NR * G4 * 4);          // 128 MB (merged only)
    const bool merged = (ws_size >= off);                       // ~336 MB needed
    if (!merged) XG_B = XG_F;                                   // sequential reuse

    init_flags<<<128, 512, 0, stream>>>(FLAGS);
    pack_whh_v3<<<128, 256, 0, stream>>>(w_hh_f, WPK_F);
    pack_whh_v3<<<128, 256, 0, stream>>>(w_hh_b, WPK_B);

    if (merged) {
        gemm_xg<<<dim3(NR / 128, G4 / 128), 256, 0, stream>>>(word, w_ih_f, b_ih_f, b_hh_f, XG_F);
        gemm_xg<<<dim3(NR / 128, G4 / 128), 256, 0, stream>>>(word, w_ih_b, b_ih_b, b_hh_b, XG_B);
        lstm_flag<<<2 * NBLK, 512, 0, stream>>>(XG_F, XG_B, WPK_F, WPK_B, HB_F, HB_B,
                                                FLAGS, FLAGS + SL * NBLK, LOUT, 0);
    } else {
        gemm_xg<<<dim3(NR / 128, G4 / 128), 256, 0, stream>>>(word, w_ih_f, b_ih_f, b_hh_f, XG_F);
        lstm_flag<<<NBLK, 512, 0, stream>>>(XG_F, XG_B, WPK_F, WPK_B, HB_F, HB_B,
                                            FLAGS, FLAGS + SL * NBLK, LOUT, 0);
        gemm_xg<<<dim3(NR / 128, G4 / 128), 256, 0, stream>>>(word, w_ih_b, b_ih_b, b_hh_b, XG_F);
        lstm_flag<<<NBLK, 512, 0, stream>>>(XG_F, XG_B, WPK_F, WPK_B, HB_F, HB_B,
                                            FLAGS, FLAGS + SL * NBLK, LOUT, 1);
    }

    bn_stats<<<C2, 256, 0, stream>>>(LOUT, MEAN, ISTD);
    fold_lin<<<TT, 256, 0, stream>>>(lin_w, lin_b, gamma, beta, MEAN, ISTD, WF, CT);
    emit_logits<<<SL, 256, 0, stream>>>(LOUT, WF, CT, Ebuf);

    crf_llh<<<BS, 64, 0, stream>>>(Ebuf, mask, labels, c_start, c_end, c_trans, RES);
    loss_reduce<<<1, 64, 0, stream>>>(RES, out);
    viterbi<<<BS, 64, 0, stream>>>(Ebuf, mask, c_start, c_end, c_trans, out + 1);
}

// Round 7
// 8895.379 us; speedup vs baseline: 1.2223x; 1.2223x over previous
//
#include <hip/hip_runtime.h>
#include <hip/hip_bf16.h>
#include <math.h>

// Problem constants
#define SL 256
#define BS 64
#define DI 1024
#define HH 512
#define TT 17
#define NR (SL*BS)        // 16384 rows
#define G4 (4*HH)         // 2048 gates
#define C2 (2*HH)         // 1024 channels
#define NBLK 128          // blocks per direction in lstm_flag (4 h-units each)

__device__ __forceinline__ float sigm(float x) { return 1.f / (1.f + expf(-x)); }

typedef float vfloat4 __attribute__((ext_vector_type(4)));
typedef __attribute__((ext_vector_type(8))) short short8v;   // 8 bf16 (4 VGPRs)
typedef __attribute__((ext_vector_type(4))) float f32x4;     // MFMA acc

// Coherent (L1/L2-bypassing, agent-visible) 16B accesses for the LSTM h
// exchange. Loads valid after wait_vm0(); stores visible after wait_vm0().
__device__ __forceinline__ void coh_load4(float4& d, const float* p) {
    asm volatile("global_load_dwordx4 %0, %1, off sc0 sc1" : "=v"(d) : "v"(p) : "memory");
}
__device__ __forceinline__ void coh_load4i(int4& d, const int* p) {
    asm volatile("global_load_dwordx4 %0, %1, off sc0 sc1" : "=v"(d) : "v"(p) : "memory");
}
__device__ __forceinline__ void coh_store4(const float4& d, float* p) {
    vfloat4 t; t.x = d.x; t.y = d.y; t.z = d.z; t.w = d.w;
    asm volatile("global_store_dwordx4 %0, %1, off sc0 sc1" :: "v"(p), "v"(t) : "memory");
}
__device__ __forceinline__ void wait_vm0() { asm volatile("s_waitcnt vmcnt(0)" ::: "memory"); }

// In-register fp32 -> bf16 hi (truncate) + bf16 lo (rne of residual).
// x = hi + lo exactly to ~2^-17 relative; dropped lo*lo term is 2^-18/term.
__device__ __forceinline__ void split8(const float4& x0, const float4& x1,
                                       short8v& h, short8v& l)
{
    const float xs[8] = {x0.x, x0.y, x0.z, x0.w, x1.x, x1.y, x1.z, x1.w};
    #pragma unroll
    for (int j = 0; j < 8; ++j) {
        const uint u   = __float_as_uint(xs[j]);
        const float hf = __uint_as_float(u & 0xFFFF0000u);   // bf16-trunc as f32
        h[j] = (short)(u >> 16);
        const float lo = xs[j] - hf;                          // exact residual
        const uint v   = __float_as_uint(lo);
        l[j] = (short)((v + 0x7FFFu + ((v >> 16) & 1u)) >> 16);   // rne
    }
}

// ---------------------------------------------------------------------------
// MFMA split-bf16 GEMM, fp32 in/out: C = X @ W^T + b1 + b2, written
// slice-major XG2[((s*SL+t)*BS+b)*16 + c], s=(n&511)>>2, c=(n>>9)*4+(n&3).
// hi/lo split done IN-KERNEL (no pack buffers, no extra workspace).
// 3 MFMA passes (hh + hl + lh), fp32 accumulate. No LDS; per-lane
// k-contiguous 32B fragment loads, L2-reused across the 128x16 grid.
// 128x128 tile, 4 waves (2x2), each wave 64x64 = 4x4 16x16x32 frags.
// Layouts: A lane: row=lane&15, k=(lane>>4)*8+j ; B(^T src): col=lane&15,
// same k ; D: col=lane&15, row=(lane>>4)*4+reg (m89-verified).
// ---------------------------------------------------------------------------
__global__ __launch_bounds__(256) void gemm_xg_mfma(
    const float* __restrict__ A,    // [NR][DI] fp32
    const float* __restrict__ W,    // [G4][DI] fp32
    const float* __restrict__ b1,
    const float* __restrict__ b2,
    float* __restrict__ C)
{
    const int tid  = threadIdx.x;
    const int lane = tid & 63;
    const int w    = tid >> 6;
    const int wm   = w >> 1, wn = w & 1;
    const int m0   = blockIdx.x * 128 + wm * 64;
    const int n0   = blockIdx.y * 128 + wn * 64;
    const int lr   = lane & 15;
    const int lk   = (lane >> 4) * 8;

    const float* pA = A + (size_t)(m0 + lr) * DI + lk;
    const float* pB = W + (size_t)(n0 + lr) * DI + lk;

    f32x4 acc[4][4];
    #pragma unroll
    for (int i = 0; i < 4; i++)
        #pragma unroll
        for (int j = 0; j < 4; j++) {
            acc[i][j][0] = 0.f; acc[i][j][1] = 0.f;
            acc[i][j][2] = 0.f; acc[i][j][3] = 0.f;
        }

    for (int k0 = 0; k0 < DI; k0 += 32) {
        short8v ah[4], al[4], bh[4], bl[4];
        #pragma unroll
        for (int i = 0; i < 4; i++) {
            const float4 a0 = *(const float4*)(pA + (size_t)i * 16 * DI + k0);
            const float4 a1 = *(const float4*)(pA + (size_t)i * 16 * DI + k0 + 4);
            split8(a0, a1, ah[i], al[i]);
            const float4 b0 = *(const float4*)(pB + (size_t)i * 16 * DI + k0);
            const float4 b1v = *(const float4*)(pB + (size_t)i * 16 * DI + k0 + 4);
            split8(b0, b1v, bh[i], bl[i]);
        }
        // pass 0: hi*hi  (16 independent MFMAs between acc reuses)
        #pragma unroll
        for (int i = 0; i < 4; i++)
            #pragma unroll
            for (int j = 0; j < 4; j++)
                acc[i][j] = __builtin_amdgcn_mfma_f32_16x16x32_bf16(ah[i], bh[j], acc[i][j], 0, 0, 0);
        // pass 1: hi*lo
        #pragma unroll
        for (int i = 0; i < 4; i++)
            #pragma unroll
            for (int j = 0; j < 4; j++)
                acc[i][j] = __builtin_amdgcn_mfma_f32_16x16x32_bf16(ah[i], bl[j], acc[i][j], 0, 0, 0);
        // pass 2: lo*hi
        #pragma unroll
        for (int i = 0; i < 4; i++)
            #pragma unroll
            for (int j = 0; j < 4; j++)
                acc[i][j] = __builtin_amdgcn_mfma_f32_16x16x32_bf16(al[i], bh[j], acc[i][j], 0, 0, 0);
    }

    #pragma unroll
    for (int j = 0; j < 4; j++) {
        const int n  = n0 + j * 16 + lr;
        const float bs = b1[n] + b2[n];
        const int u  = n & 511, g = n >> 9;
        const int s0 = u >> 2,  c = g * 4 + (u & 3);
        #pragma unroll
        for (int i = 0; i < 4; i++) {
            #pragma unroll
            for (int r = 0; r < 4; r++) {
                const int m  = m0 + i * 16 + (lane >> 4) * 4 + r;
                const int mt = m >> 6, mb = m & 63;
                C[((((size_t)s0 * SL + mt) * BS + mb) << 4) + c] = acc[i][j][r] + bs;
            }
        }
    }
}

// ---------------------------------------------------------------------------
// Pack w_hh (2048x512) -> wp[128 slices][512 k][24] (cols c=g*4+uu, pad 16..23)
// ---------------------------------------------------------------------------
__global__ __launch_bounds__(256) void pack_whh_v3(const float* __restrict__ whh,
                                                   float* __restrict__ wp)
{
    const int s = blockIdx.x;
    for (int idx = threadIdx.x; idx < 512 * 24; idx += 256) {
        const int k = idx / 24, c = idx % 24;
        float v = 0.f;
        if (c < 16) {
            const int g = c >> 2, uu = c & 3;
            v = whh[(size_t)(g * 512 + 4 * s + uu) * HH + k];
        }
        wp[(size_t)s * 12288 + idx] = v;
    }
}

__global__ __launch_bounds__(512) void init_flags(int* __restrict__ f)
{
    f[blockIdx.x * 512 + threadIdx.x] = 0;   // 128*512 = 2*SL*NBLK ints
}

// ---------------------------------------------------------------------------
// Flag-pipelined LSTM (round-2 verified version, 3.74 ms). Grid 256 merged
// (1 block/CU) or 128. Block s owns h-units {4s..4s+3}. Weights LDS-resident.
// Poll prev flags (uncached int4) -> stage H(t-1) in 4 chunks of coherent
// dwordx4 (next chunk prefetched during compute) -> GEMM -> shfl k-reduce ->
// skewed LDS cross-wave reduce -> gates (c in regs) -> publish + flag.
// ---------------------------------------------------------------------------
__global__ __launch_bounds__(512, 2) void lstm_flag(
    const float* __restrict__ xg_f, const float* __restrict__ xg_b,  // slice-major
    const float* __restrict__ wp_f, const float* __restrict__ wp_b,
    float* __restrict__ Hf, float* __restrict__ Hb,
    int* __restrict__ flag_f, int* __restrict__ flag_b,
    float* __restrict__ out,          // channel-major [C2][NR]
    int dir_base)
{
    __shared__ float w_s[512 * 24];              // 49152 B, persistent
    __shared__ float hs[128 * 68];               // 34816 B, reused per chunk
    __shared__ float g_s[16 * 65];               //  4160 B
    __shared__ float hpub[256];                  //  1024 B
    float* const part = hs;                      // [8][1088] overlay (exact fit)

    const int dir = dir_base + (blockIdx.x >> 7);
    const int s   = blockIdx.x & 127;
    const float* xg  = dir ? xg_b : xg_f;
    const float* wp  = dir ? wp_b : wp_f;
    float* Hbuf      = dir ? Hb : Hf;
    int*   flag      = dir ? flag_b : flag_f;
    const int reverse = dir;
    const int col_off = dir * HH;

    const int tid = threadIdx.x;
    const int ks  = tid >> 4;        // 0..31 k-slice
    const int bt  = (tid >> 1) & 7;  // 0..7 batch tile
    const int ct  = tid & 1;         // 0..1 col tile (8 cols each)
    const int wv  = tid >> 6;        // wave 0..7

    // stage weights once (3072 float4)
    {
        const float4* src = (const float4*)(wp + (size_t)s * 12288);
        float4* dst = (float4*)w_s;
        for (int i = tid; i < 3072; i += 512) dst[i] = src[i];
    }

    const float* xgs = xg + (size_t)s * (SL * 1024);
    float cst = 0.f;                  // c-state: tid<256 owns (b=tid&63, uu=tid>>6)
    float4 r[4];
    float4 acc[8][2];

    for (int step = 0; step < SL; ++step) {
        const int t = reverse ? (SL - 1 - step) : step;
        const float myxg0 = xgs[t * 1024 + tid];
        const float myxg1 = xgs[t * 1024 + 512 + tid];

        if (step > 0) {
            if (tid < 32) {
                const int* fp = flag + (step - 1) * NBLK + tid * 4;
                int4 f;
                for (;;) {
                    coh_load4i(f, fp);
                    wait_vm0();
                    if (f.x & f.y & f.z & f.w) break;
                    __builtin_amdgcn_s_sleep(1);
                }
            }
            __syncthreads();   // flags seen; also protects w_s/hs reuse

            const float* hsrc = Hbuf + ((step + 1) & 1) * (512 * 64);
            #pragma unroll
            for (int i = 0; i < 4; ++i)
                coh_load4(r[i], hsrc + (size_t)(i * 512 + tid) * 4);

            #pragma unroll
            for (int i = 0; i < 8; ++i) {
                acc[i][0] = make_float4(0.f, 0.f, 0.f, 0.f);
                acc[i][1] = make_float4(0.f, 0.f, 0.f, 0.f);
            }

            for (int kc = 0; kc < 4; ++kc) {
                if (kc) __syncthreads();           // prev chunk consumed
                wait_vm0();
                #pragma unroll
                for (int i = 0; i < 4; ++i) {
                    const int idx = i * 512 + tid;        // float4 index in chunk
                    const int k = idx >> 4, b4 = (idx & 15) * 4;
                    *(float4*)&hs[k * 68 + b4] = r[i];
                }
                __syncthreads();                   // hs ready
                if (kc < 3) {                      // prefetch next chunk during compute
                    const float* base = hsrc + (size_t)(kc + 1) * 8192;
                    #pragma unroll
                    for (int i = 0; i < 4; ++i)
                        coh_load4(r[i], base + (size_t)(i * 512 + tid) * 4);
                }
                #pragma unroll
                for (int j = 0; j < 4; ++j) {
                    const int kk = ks + 32 * j;
                    const int kg = kc * 128 + kk;
                    const float4 w0 = *(const float4*)&w_s[kg * 24 + ct * 8];
                    const float4 w1 = *(const float4*)&w_s[kg * 24 + ct * 8 + 4];
                    const float* hp = &hs[kk * 68 + 8 * bt];
                    const float2 h01 = *(const float2*)(hp + 0);
                    const float2 h23 = *(const float2*)(hp + 2);
                    const float2 h45 = *(const float2*)(hp + 4);
                    const float2 h67 = *(const float2*)(hp + 6);
                    const float hv[8] = {h01.x, h01.y, h23.x, h23.y, h45.x, h45.y, h67.x, h67.y};
                    #pragma unroll
                    for (int i = 0; i < 8; ++i) {
                        acc[i][0].x = fmaf(hv[i], w0.x, acc[i][0].x);
                        acc[i][0].y = fmaf(hv[i], w0.y, acc[i][0].y);
                        acc[i][0].z = fmaf(hv[i], w0.z, acc[i][0].z);
                        acc[i][0].w = fmaf(hv[i], w0.w, acc[i][0].w);
                        acc[i][1].x = fmaf(hv[i], w1.x, acc[i][1].x);
                        acc[i][1].y = fmaf(hv[i], w1.y, acc[i][1].y);
                        acc[i][1].z = fmaf(hv[i], w1.z, acc[i][1].z);
                        acc[i][1].w = fmaf(hv[i], w1.w, acc[i][1].w);
                    }
                }
            }
            // k-reduce within wave (ks bits 4,5 of lane)
            #pragma unroll
            for (int i = 0; i < 8; ++i)
                #pragma unroll
                for (int p = 0; p < 2; ++p) {
                    acc[i][p].x += __shfl_xor(acc[i][p].x, 16);
                    acc[i][p].y += __shfl_xor(acc[i][p].y, 16);
                    acc[i][p].z += __shfl_xor(acc[i][p].z, 16);
                    acc[i][p].w += __shfl_xor(acc[i][p].w, 16);
                    acc[i][p].x += __shfl_xor(acc[i][p].x, 32);
                    acc[i][p].y += __shfl_xor(acc[i][p].y, 32);
                    acc[i][p].z += __shfl_xor(acc[i][p].z, 32);
                    acc[i][p].w += __shfl_xor(acc[i][p].w, 32);
                }
            __syncthreads();                       // hs reads done; part overlays hs
            if ((tid & 63) < 16) {                 // skew bt*8 breaks bank aliasing
                #pragma unroll
                for (int i = 0; i < 8; ++i) {
                    const int base = wv * 1088 + (8 * bt + i) * 16 + ct * 8 + bt * 8;
                    *(float4*)&part[base + 0] = acc[i][0];
                    *(float4*)&part[base + 4] = acc[i][1];
                }
            }
            __syncthreads();
        }

        // cross-wave reduce + xg: thread owns gates {tid, tid+512}; gate = b*16+c
        {
            float v0 = myxg0, v1 = myxg1;
            if (step > 0) {
                const int gA = tid, gB = tid + 512;
                const int iA = gA + 8 * (gA >> 7);
                const int iB = gB + 8 * (gB >> 7);
                #pragma unroll
                for (int w = 0; w < 8; ++w) {
                    v0 += part[w * 1088 + iA];
                    v1 += part[w * 1088 + iB];
                }
            }
            g_s[(tid & 15) * 65 + (tid >> 4)] = v0;
            {
                const int gB = tid + 512;
                g_s[(gB & 15) * 65 + (gB >> 4)] = v1;
            }
        }
        __syncthreads();

        if (tid < 256) {
            const int b = tid & 63, uu = tid >> 6;      // uu 0..3
            const float ig = sigm(g_s[(0  + uu) * 65 + b]);
            const float fg = sigm(g_s[(4  + uu) * 65 + b]);
            const float gg = tanhf(g_s[(8  + uu) * 65 + b]);
            const float og = sigm(g_s[(12 + uu) * 65 + b]);
            cst = fg * cst + ig * gg;
            hpub[tid] = og * tanhf(cst);           // [uu][b]
        }
        __syncthreads();
        if (tid < 16) {                            // coalesced publication (1 KB)
            const float4 v = *(const float4*)&hpub[tid * 16];
            coh_store4(v, Hbuf + (step & 1) * (512 * 64) + s * 256 + tid * 16);
            *(float4*)(out + (size_t)(col_off + 4 * s + (tid >> 2)) * NR
                           + (size_t)t * 64 + (tid & 3) * 16) = v;
        }
        if (wv == 0) wait_vm0();                   // h at coherent point
        __syncthreads();
        if (tid == 0)
            __hip_atomic_store(flag + step * NBLK + s, 1,
                               __ATOMIC_RELEASE, __HIP_MEMORY_SCOPE_AGENT);
    }
}

// ---------------------------------------------------------------------------
// BatchNorm stats over channel-major X2 [C2][NR]: block per channel
// ---------------------------------------------------------------------------
__global__ __launch_bounds__(256) void bn_stats(
    const float* __restrict__ X2, float* __restrict__ mean, float* __restrict__ istd)
{
    const int ch = blockIdx.x, tid = threadIdx.x;
    const float* base = X2 + (size_t)ch * NR;
    __shared__ float red[256];
    float s = 0.f;
    for (int i = tid * 4; i < NR; i += 1024) {
        const float4 v = *(const float4*)(base + i);
        s += v.x + v.y + v.z + v.w;
    }
    red[tid] = s; __syncthreads();
    for (int o = 128; o; o >>= 1) { if (tid < o) red[tid] += red[tid + o]; __syncthreads(); }
    const float mu = red[0] * (1.f / NR);
    __syncthreads();
    float vv = 0.f;
    for (int i = tid * 4; i < NR; i += 1024) {
        const float4 v = *(const float4*)(base + i);
        const float d0 = v.x - mu, d1 = v.y - mu, d2 = v.z - mu, d3 = v.w - mu;
        vv += d0 * d0 + d1 * d1 + d2 * d2 + d3 * d3;
    }
    red[tid] = vv; __syncthreads();
    for (int o = 128; o; o >>= 1) { if (tid < o) red[tid] += red[tid + o]; __syncthreads(); }
    if (tid == 0) { mean[ch] = mu; istd[ch] = rsqrtf(red[0] * (1.f / NR) + 1e-5f); }
}

// ---------------------------------------------------------------------------
// Fold BN into linear
// ---------------------------------------------------------------------------
__global__ void fold_lin(const float* __restrict__ lin_w, const float* __restrict__ lin_b,
                         const float* __restrict__ gamma, const float* __restrict__ beta,
                         const float* __restrict__ mean, const float* __restrict__ istd,
                         float* __restrict__ Wf, float* __restrict__ ct)
{
    const int t = blockIdx.x, tid = threadIdx.x;
    __shared__ float red[256];
    float acc = 0.f;
    for (int cc = tid; cc < C2; cc += 256) {
        const float w = lin_w[t * C2 + cc];
        const float g = gamma[cc] * istd[cc];
        Wf[t * C2 + cc] = w * g;
        acc = fmaf(beta[cc] - mean[cc] * g, w, acc);
    }
    red[tid] = acc; __syncthreads();
    for (int o = 128; o; o >>= 1) { if (tid < o) red[tid] += red[tid + o]; __syncthreads(); }
    if (tid == 0) ct[t] = red[0] + lin_b[t];
}

// ---------------------------------------------------------------------------
// Emission logits from channel-major X2: block per timestep t, lane = batch.
// ---------------------------------------------------------------------------
__global__ __launch_bounds__(256) void emit_logits(
    const float* __restrict__ X2, const float* __restrict__ Wf,
    const float* __restrict__ ct, float* __restrict__ E)
{
    __shared__ float ps[256 * TT];               // 17408 B partials
    const int t = blockIdx.x;
    const int tid = threadIdx.x;
    const int b = tid & 63, p = tid >> 6;
    const float* xb = X2 + (size_t)t * 64 + b;

    float acc[TT];
    #pragma unroll
    for (int k = 0; k < TT; k++) acc[k] = 0.f;

    for (int c0 = p * 256; c0 < p * 256 + 256; c0 += 4) {
        const float x0 = xb[(size_t)(c0 + 0) * NR];
        const float x1 = xb[(size_t)(c0 + 1) * NR];
        const float x2 = xb[(size_t)(c0 + 2) * NR];
        const float x3 = xb[(size_t)(c0 + 3) * NR];
        #pragma unroll
        for (int k = 0; k < TT; k++) {
            const float4 w = *(const float4*)&Wf[k * C2 + c0];   // wave-uniform
            acc[k] = fmaf(x0, w.x, fmaf(x1, w.y, fmaf(x2, w.z, fmaf(x3, w.w, acc[k]))));
        }
    }
    #pragma unroll
    for (int k = 0; k < TT; k++) ps[tid * TT + k] = acc[k];
    __syncthreads();
    if (tid < 64) {
        float* Er = E + ((size_t)tid * SL + t) * TT;
        #pragma unroll
        for (int k = 0; k < TT; k++) {
            float v = ct[k];
            #pragma unroll
            for (int q = 0; q < 4; q++) v += ps[(q * 64 + tid) * TT + k];
            Er[k] = v;
        }
    }
}

// ---------------------------------------------------------------------------
// CRF log-likelihood per batch element
// ---------------------------------------------------------------------------
__global__ __launch_bounds__(64) void crf_llh(
    const float* __restrict__ E, const int* __restrict__ mask,
    const int* __restrict__ labels, const float* __restrict__ startv,
    const float* __restrict__ endv, const float* __restrict__ trans,
    float* __restrict__ res)
{
    const int b = blockIdx.x, lane = threadIdx.x;
    __shared__ float tr[TT][TT];
    for (int i = lane; i < TT * TT; i += 64) tr[i / TT][i % TT] = trans[i];
    __syncthreads();
    const float* Eb = E + (size_t)b * SL * TT;
    const int j = (lane < TT) ? lane : 0;

    float alpha = -1e30f;
    if (lane < TT) alpha = startv[lane] + Eb[lane];

    float numacc = 0.f; int len = 0;
    for (int t = lane; t < SL; t += 64) {
        const int mt = mask[t * BS + b];
        len += (mt != 0);
        if (t >= 1 && mt) {
            const int yp = labels[(t - 1) * BS + b];
            const int yt = labels[t * BS + b];
            numacc += tr[yp][yt] + Eb[t * TT + yt];
        }
    }
    for (int off = 32; off; off >>= 1) {
        numacc += __shfl_xor(numacc, off);
        len += __shfl_xor(len, off);
    }

    for (int t = 1; t < SL; ++t) {
        const int mt = mask[t * BS + b];
        if (mt) {
            float av[TT];
            #pragma unroll
            for (int i = 0; i < TT; i++) av[i] = __shfl(alpha, i);
            const float e = (lane < TT) ? Eb[t * TT + lane] : 0.f;
            float mx = -1e30f;
            #pragma unroll
            for (int i = 0; i < TT; i++) mx = fmaxf(mx, av[i] + tr[i][j]);
            float ssum = 0.f;
            #pragma unroll
            for (int i = 0; i < TT; i++) ssum += expf(av[i] + tr[i][j] - mx);
            const float nxt = mx + logf(ssum) + e;
            if (lane < TT) alpha = nxt;
        }
    }
    float v = (lane < TT) ? alpha + endv[lane] : -1e30f;
    float mx = v;
    for (int off = 32; off; off >>= 1) mx = fmaxf(mx, __shfl_xor(mx, off));
    float se = (lane < TT) ? expf(v - mx) : 0.f;
    for (int off = 32; off; off >>= 1) se += __shfl_xor(se, off);
    const float Z = mx + logf(se);

    if (lane == 0) {
        const int y0 = labels[b];
        float num = startv[y0] + Eb[y0] + numacc;
        const int last = len - 1;
        const int yl = labels[last * BS + b];
        num += endv[yl];
        res[b] = num - Z;
    }
}

__global__ __launch_bounds__(64) void loss_reduce(const float* __restrict__ res, float* __restrict__ out)
{
    const int lane = threadIdx.x;
    float v = res[lane];
    for (int off = 32; off; off >>= 1) v += __shfl_xor(v, off);
    if (lane == 0) out[0] = -v;
}

// ---------------------------------------------------------------------------
// Viterbi per batch element
// ---------------------------------------------------------------------------
__global__ __launch_bounds__(64) void viterbi(
    const float* __restrict__ E, const int* __restrict__ mask,
    const float* __restrict__ startv, const float* __restrict__ endv,
    const float* __restrict__ trans, float* __restrict__ preds)
{
    const int b = blockIdx.x, lane = threadIdx.x;
    __shared__ float tr[TT][TT];
    __shared__ unsigned char bp[SL][TT];
    for (int i = lane; i < TT * TT; i += 64) tr[i / TT][i % TT] = trans[i];
    __syncthreads();
    const float* Eb = E + (size_t)b * SL * TT;
    const int j = (lane < TT) ? lane : 0;

    float score = (lane < TT) ? startv[lane] + Eb[lane] : -1e30f;
    for (int t = 1; t < SL; ++t) {
        float av[TT];
        #pragma unroll
        for (int i = 0; i < TT; i++) av[i] = __shfl(score, i);
        float best = -1e30f; int bi = 0;
        #pragma unroll
        for (int i = 0; i < TT; i++) {
            const float cand = av[i] + tr[i][j];
            if (cand > best) { best = cand; bi = i; }   // strict > => first max
        }
        const int mt = mask[t * BS + b];
        if (lane < TT) {
            bp[t][lane] = (unsigned char)bi;
            if (mt) score = best + Eb[t * TT + lane];
        }
    }
    float v = (lane < TT) ? score + endv[lane] : -1e30f;
    float mx = v;
    for (int off = 32; off; off >>= 1) mx = fmaxf(mx, __shfl_xor(mx, off));
    unsigned long long ball = __ballot(v == mx);
    const int last_tag = __ffsll(ball) - 1;
    __syncthreads();

    if (lane == 0) {
        int tag = last_tag;
        float* pb = preds + (size_t)b * SL;
        for (int t = SL - 1; t >= 1; --t) {
            const int mt = mask[t * BS + b];
            pb[t] = mt ? (float)tag : 0.f;
            if (mt) tag = bp[t][tag];
        }
        pb[0] = mask[b] ? (float)tag : 0.f;
    }
}

// ---------------------------------------------------------------------------
extern "C" void kernel_launch(void* const* d_in, const int* in_sizes, int n_in,
                              void* d_out, int out_size, void* d_ws, size_t ws_size,
                              hipStream_t stream)
{
    const float* word    = (const float*)d_in[0];
    const int*   mask    = (const int*)  d_in[1];
    const int*   labels  = (const int*)  d_in[2];
    const float* w_ih_f  = (const float*)d_in[3];
    const float* w_hh_f  = (const float*)d_in[4];
    const float* b_ih_f  = (const float*)d_in[5];
    const float* b_hh_f  = (const float*)d_in[6];
    const float* w_ih_b  = (const float*)d_in[7];
    const float* w_hh_b  = (const float*)d_in[8];
    const float* b_ih_b  = (const float*)d_in[9];
    const float* b_hh_b  = (const float*)d_in[10];
    const float* gamma   = (const float*)d_in[11];
    const float* beta    = (const float*)d_in[12];
    const float* lin_w   = (const float*)d_in[13];
    const float* lin_b   = (const float*)d_in[14];
    const float* c_start = (const float*)d_in[15];
    const float* c_end   = (const float*)d_in[16];
    const float* c_trans = (const float*)d_in[17];
    float* out = (float*)d_out;
    (void)in_sizes; (void)n_in; (void)out_size;

    char* ws = (char*)d_ws;
    size_t off = 0;
    auto alloc = [&](size_t bytes) {
        void* p = ws + off;
        off += (bytes + 255) & ~(size_t)255;
        return p;
    };
    // Layout byte-identical to the round-2 verified version (~335 MB merged).
    float* XG_F  = (float*)alloc((size_t)NR * G4 * 4);          // 128 MB
    float* WPK_F = (float*)alloc((size_t)128 * 12288 * 4);      // 6.3 MB
    float* WPK_B = (float*)alloc((size_t)128 * 12288 * 4);      // 6.3 MB
    float* LOUT  = (float*)alloc((size_t)NR * C2 * 4);          // 64 MB channel-major
    float* HB_F  = (float*)alloc((size_t)2 * 512 * 64 * 4);     // 256 KB
    float* HB_B  = (float*)alloc((size_t)2 * 512 * 64 * 4);     // 256 KB
    int*   FLAGS = (int*)  alloc((size_t)2 * SL * NBLK * 4);    // 256 KB
    float* MEAN  = (float*)alloc(C2 * 4);
    float* ISTD  = (float*)alloc(C2 * 4);
    float* WF    = (float*)alloc(TT * C2 * 4);
    float* CT    = (float*)alloc(TT * 4);
    float* Ebuf  = (float*)alloc((size_t)BS * SL * TT * 4);
    float* RES   = (float*)alloc(BS * 4);
    float* XG_B  = (float*)alloc((size_t)NR * G4 * 4);          // 128 MB (merged only)
    const bool merged = (ws_size >= off);                       // ~336 MB needed
    if (!merged) XG_B = XG_F;                                   // sequential reuse

    init_flags<<<128, 512, 0, stream>>>(FLAGS);
    pack_whh_v3<<<128, 256, 0, stream>>>(w_hh_f, WPK_F);
    pack_whh_v3<<<128, 256, 0, stream>>>(w_hh_b, WPK_B);

    if (merged) {
        gemm_xg_mfma<<<dim3(NR / 128, G4 / 128), 256, 0, stream>>>(word, w_ih_f, b_ih_f, b_hh_f, XG_F);
        gemm_xg_mfma<<<dim3(NR / 128, G4 / 128), 256, 0, stream>>>(word, w_ih_b, b_ih_b, b_hh_b, XG_B);
        lstm_flag<<<2 * NBLK, 512, 0, stream>>>(XG_F, XG_B, WPK_F, WPK_B, HB_F, HB_B,
                                                FLAGS, FLAGS + SL * NBLK, LOUT, 0);
    } else {
        gemm_xg_mfma<<<dim3(NR / 128, G4 / 128), 256, 0, stream>>>(word, w_ih_f, b_ih_f, b_hh_f, XG_F);
        lstm_flag<<<NBLK, 512, 0, stream>>>(XG_F, XG_B, WPK_F, WPK_B, HB_F, HB_B,
                                            FLAGS, FLAGS + SL * NBLK, LOUT, 0);
        gemm_xg_mfma<<<dim3(NR / 128, G4 / 128), 256, 0, stream>>>(word, w_ih_b, b_ih_b, b_hh_b, XG_F);
        lstm_flag<<<NBLK, 512, 0, stream>>>(XG_F, XG_B, WPK_F, WPK_B, HB_F, HB_B,
                                            FLAGS, FLAGS + SL * NBLK, LOUT, 1);
    }

    bn_stats<<<C2, 256, 0, stream>>>(LOUT, MEAN, ISTD);
    fold_lin<<<TT, 256, 0, stream>>>(lin_w, lin_b, gamma, beta, MEAN, ISTD, WF, CT);
    emit_logits<<<SL, 256, 0, stream>>>(LOUT, WF, CT, Ebuf);

    crf_llh<<<BS, 64, 0, stream>>>(Ebuf, mask, labels, c_start, c_end, c_trans, RES);
    loss_reduce<<<1, 64, 0, stream>>>(RES, out);
    viterbi<<<BS, 64, 0, stream>>>(Ebuf, mask, c_start, c_end, c_trans, out + 1);
}

// Round 8
// 8762.337 us; speedup vs baseline: 1.2409x; 1.0152x over previous
//
#include <hip/hip_runtime.h>
#include <hip/hip_bf16.h>
#include <math.h>

// Problem constants
#define SL 256
#define BS 64
#define DI 1024
#define HH 512
#define TT 17
#define NR (SL*BS)        // 16384 rows
#define G4 (4*HH)         // 2048 gates
#define C2 (2*HH)         // 1024 channels
#define NBLK 128          // blocks per direction in lstm_flag (4 h-units each)

__device__ __forceinline__ float sigm(float x) { return 1.f / (1.f + expf(-x)); }

typedef float vfloat4 __attribute__((ext_vector_type(4)));
typedef __attribute__((ext_vector_type(8))) short short8v;   // 8 bf16 (4 VGPRs)
typedef __attribute__((ext_vector_type(4))) float f32x4;     // MFMA acc

// Coherent (L1/L2-bypassing, agent-visible) 16B accesses for the LSTM h
// exchange. Loads valid after wait_vm0(); stores visible after wait_vm0().
__device__ __forceinline__ void coh_load4(float4& d, const float* p) {
    asm volatile("global_load_dwordx4 %0, %1, off sc0 sc1" : "=v"(d) : "v"(p) : "memory");
}
__device__ __forceinline__ void coh_load4i(int4& d, const int* p) {
    asm volatile("global_load_dwordx4 %0, %1, off sc0 sc1" : "=v"(d) : "v"(p) : "memory");
}
__device__ __forceinline__ void coh_store4(const float4& d, float* p) {
    vfloat4 t; t.x = d.x; t.y = d.y; t.z = d.z; t.w = d.w;
    asm volatile("global_store_dwordx4 %0, %1, off sc0 sc1" :: "v"(p), "v"(t) : "memory");
}
__device__ __forceinline__ void wait_vm0() { asm volatile("s_waitcnt vmcnt(0)" ::: "memory"); }

// In-register fp32 -> bf16 hi (truncate) + bf16 lo (rne of residual).
// x = hi + lo exactly to ~2^-17 relative; dropped lo*lo term is 2^-18/term.
__device__ __forceinline__ void split8(const float4& x0, const float4& x1,
                                       short8v& h, short8v& l)
{
    const float xs[8] = {x0.x, x0.y, x0.z, x0.w, x1.x, x1.y, x1.z, x1.w};
    #pragma unroll
    for (int j = 0; j < 8; ++j) {
        const uint u   = __float_as_uint(xs[j]);
        const float hf = __uint_as_float(u & 0xFFFF0000u);   // bf16-trunc as f32
        h[j] = (short)(u >> 16);
        const float lo = xs[j] - hf;                          // exact residual
        const uint v   = __float_as_uint(lo);
        l[j] = (short)((v + 0x7FFFu + ((v >> 16) & 1u)) >> 16);   // rne
    }
}

// ---------------------------------------------------------------------------
// MFMA split-bf16 GEMM, fp32 in/out: C = X @ W^T + b1 + b2, written
// slice-major XG2[((s*SL+t)*BS+b)*16 + c], s=(n&511)>>2, c=(n>>9)*4+(n&3).
// hi/lo split done IN-KERNEL (no pack buffers, no extra workspace).
// 3 MFMA passes (hh + hl + lh), fp32 accumulate. No LDS; per-lane
// k-contiguous 32B fragment loads. GRID IS (n-tiles=16, m-tiles=128) with
// n fastest: 16 consecutive blocks share one 512KB A-panel (L2-temporal),
// concurrent working set ~ 16 A-panels (8MB) + full B (8MB) ~ L2-resident.
// Round-7 grid (m fastest) streamed ALL 64MB of A per n-tile -> 1GB of
// L3-level A traffic per GEMM; this grid reads A once.
// 128x128 tile, 4 waves (2x2), each wave 64x64 = 4x4 16x16x32 frags.
// Layouts: A lane: row=lane&15, k=(lane>>4)*8+j ; B(^T src): col=lane&15,
// same k ; D: col=lane&15, row=(lane>>4)*4+reg (m89-verified).
// ---------------------------------------------------------------------------
__global__ __launch_bounds__(256) void gemm_xg_mfma(
    const float* __restrict__ A,    // [NR][DI] fp32
    const float* __restrict__ W,    // [G4][DI] fp32
    const float* __restrict__ b1,
    const float* __restrict__ b2,
    float* __restrict__ C)
{
    const int tid  = threadIdx.x;
    const int lane = tid & 63;
    const int w    = tid >> 6;
    const int wm   = w >> 1, wn = w & 1;
    const int m0   = blockIdx.y * 128 + wm * 64;   // m-tile = slow grid dim
    const int n0   = blockIdx.x * 128 + wn * 64;   // n-tile = fast grid dim
    const int lr   = lane & 15;
    const int lk   = (lane >> 4) * 8;

    const float* pA = A + (size_t)(m0 + lr) * DI + lk;
    const float* pB = W + (size_t)(n0 + lr) * DI + lk;

    f32x4 acc[4][4];
    #pragma unroll
    for (int i = 0; i < 4; i++)
        #pragma unroll
        for (int j = 0; j < 4; j++) {
            acc[i][j][0] = 0.f; acc[i][j][1] = 0.f;
            acc[i][j][2] = 0.f; acc[i][j][3] = 0.f;
        }

    for (int k0 = 0; k0 < DI; k0 += 32) {
        short8v ah[4], al[4], bh[4], bl[4];
        #pragma unroll
        for (int i = 0; i < 4; i++) {
            const float4 a0 = *(const float4*)(pA + (size_t)i * 16 * DI + k0);
            const float4 a1 = *(const float4*)(pA + (size_t)i * 16 * DI + k0 + 4);
            split8(a0, a1, ah[i], al[i]);
            const float4 b0 = *(const float4*)(pB + (size_t)i * 16 * DI + k0);
            const float4 b1v = *(const float4*)(pB + (size_t)i * 16 * DI + k0 + 4);
            split8(b0, b1v, bh[i], bl[i]);
        }
        // pass 0: hi*hi  (16 independent MFMAs between acc reuses)
        #pragma unroll
        for (int i = 0; i < 4; i++)
            #pragma unroll
            for (int j = 0; j < 4; j++)
                acc[i][j] = __builtin_amdgcn_mfma_f32_16x16x32_bf16(ah[i], bh[j], acc[i][j], 0, 0, 0);
        // pass 1: hi*lo
        #pragma unroll
        for (int i = 0; i < 4; i++)
            #pragma unroll
            for (int j = 0; j < 4; j++)
                acc[i][j] = __builtin_amdgcn_mfma_f32_16x16x32_bf16(ah[i], bl[j], acc[i][j], 0, 0, 0);
        // pass 2: lo*hi
        #pragma unroll
        for (int i = 0; i < 4; i++)
            #pragma unroll
            for (int j = 0; j < 4; j++)
                acc[i][j] = __builtin_amdgcn_mfma_f32_16x16x32_bf16(al[i], bh[j], acc[i][j], 0, 0, 0);
    }

    #pragma unroll
    for (int j = 0; j < 4; j++) {
        const int n  = n0 + j * 16 + lr;
        const float bs = b1[n] + b2[n];
        const int u  = n & 511, g = n >> 9;
        const int s0 = u >> 2,  c = g * 4 + (u & 3);
        #pragma unroll
        for (int i = 0; i < 4; i++) {
            #pragma unroll
            for (int r = 0; r < 4; r++) {
                const int m  = m0 + i * 16 + (lane >> 4) * 4 + r;
                const int mt = m >> 6, mb = m & 63;
                C[((((size_t)s0 * SL + mt) * BS + mb) << 4) + c] = acc[i][j][r] + bs;
            }
        }
    }
}

// ---------------------------------------------------------------------------
// Pack w_hh (2048x512) -> wp[128 slices][512 k][24] (cols c=g*4+uu, pad 16..23)
// ---------------------------------------------------------------------------
__global__ __launch_bounds__(256) void pack_whh_v3(const float* __restrict__ whh,
                                                   float* __restrict__ wp)
{
    const int s = blockIdx.x;
    for (int idx = threadIdx.x; idx < 512 * 24; idx += 256) {
        const int k = idx / 24, c = idx % 24;
        float v = 0.f;
        if (c < 16) {
            const int g = c >> 2, uu = c & 3;
            v = whh[(size_t)(g * 512 + 4 * s + uu) * HH + k];
        }
        wp[(size_t)s * 12288 + idx] = v;
    }
}

__global__ __launch_bounds__(512) void init_flags(int* __restrict__ f)
{
    f[blockIdx.x * 512 + threadIdx.x] = 0;   // 128*512 = 2*SL*NBLK ints
}

// ---------------------------------------------------------------------------
// Flag-pipelined LSTM (round-2 verified version, 3.6 ms). Grid 256 merged
// (1 block/CU) or 128. Block s owns h-units {4s..4s+3}. Weights LDS-resident.
// Poll prev flags (uncached int4) -> stage H(t-1) in 4 chunks of coherent
// dwordx4 (next chunk prefetched during compute) -> GEMM -> shfl k-reduce ->
// skewed LDS cross-wave reduce -> gates (c in regs) -> publish + flag.
// ---------------------------------------------------------------------------
__global__ __launch_bounds__(512, 2) void lstm_flag(
    const float* __restrict__ xg_f, const float* __restrict__ xg_b,  // slice-major
    const float* __restrict__ wp_f, const float* __restrict__ wp_b,
    float* __restrict__ Hf, float* __restrict__ Hb,
    int* __restrict__ flag_f, int* __restrict__ flag_b,
    float* __restrict__ out,          // channel-major [C2][NR]
    int dir_base)
{
    __shared__ float w_s[512 * 24];              // 49152 B, persistent
    __shared__ float hs[128 * 68];               // 34816 B, reused per chunk
    __shared__ float g_s[16 * 65];               //  4160 B
    __shared__ float hpub[256];                  //  1024 B
    float* const part = hs;                      // [8][1088] overlay (exact fit)

    const int dir = dir_base + (blockIdx.x >> 7);
    const int s   = blockIdx.x & 127;
    const float* xg  = dir ? xg_b : xg_f;
    const float* wp  = dir ? wp_b : wp_f;
    float* Hbuf      = dir ? Hb : Hf;
    int*   flag      = dir ? flag_b : flag_f;
    const int reverse = dir;
    const int col_off = dir * HH;

    const int tid = threadIdx.x;
    const int ks  = tid >> 4;        // 0..31 k-slice
    const int bt  = (tid >> 1) & 7;  // 0..7 batch tile
    const int ct  = tid & 1;         // 0..1 col tile (8 cols each)
    const int wv  = tid >> 6;        // wave 0..7

    // stage weights once (3072 float4)
    {
        const float4* src = (const float4*)(wp + (size_t)s * 12288);
        float4* dst = (float4*)w_s;
        for (int i = tid; i < 3072; i += 512) dst[i] = src[i];
    }

    const float* xgs = xg + (size_t)s * (SL * 1024);
    float cst = 0.f;                  // c-state: tid<256 owns (b=tid&63, uu=tid>>6)
    float4 r[4];
    float4 acc[8][2];

    for (int step = 0; step < SL; ++step) {
        const int t = reverse ? (SL - 1 - step) : step;
        const float myxg0 = xgs[t * 1024 + tid];
        const float myxg1 = xgs[t * 1024 + 512 + tid];

        if (step > 0) {
            if (tid < 32) {
                const int* fp = flag + (step - 1) * NBLK + tid * 4;
                int4 f;
                for (;;) {
                    coh_load4i(f, fp);
                    wait_vm0();
                    if (f.x & f.y & f.z & f.w) break;
                    __builtin_amdgcn_s_sleep(1);
                }
            }
            __syncthreads();   // flags seen; also protects w_s/hs reuse

            const float* hsrc = Hbuf + ((step + 1) & 1) * (512 * 64);
            #pragma unroll
            for (int i = 0; i < 4; ++i)
                coh_load4(r[i], hsrc + (size_t)(i * 512 + tid) * 4);

            #pragma unroll
            for (int i = 0; i < 8; ++i) {
                acc[i][0] = make_float4(0.f, 0.f, 0.f, 0.f);
                acc[i][1] = make_float4(0.f, 0.f, 0.f, 0.f);
            }

            for (int kc = 0; kc < 4; ++kc) {
                if (kc) __syncthreads();           // prev chunk consumed
                wait_vm0();
                #pragma unroll
                for (int i = 0; i < 4; ++i) {
                    const int idx = i * 512 + tid;        // float4 index in chunk
                    const int k = idx >> 4, b4 = (idx & 15) * 4;
                    *(float4*)&hs[k * 68 + b4] = r[i];
                }
                __syncthreads();                   // hs ready
                if (kc < 3) {                      // prefetch next chunk during compute
                    const float* base = hsrc + (size_t)(kc + 1) * 8192;
                    #pragma unroll
                    for (int i = 0; i < 4; ++i)
                        coh_load4(r[i], base + (size_t)(i * 512 + tid) * 4);
                }
                #pragma unroll
                for (int j = 0; j < 4; ++j) {
                    const int kk = ks + 32 * j;
                    const int kg = kc * 128 + kk;
                    const float4 w0 = *(const float4*)&w_s[kg * 24 + ct * 8];
                    const float4 w1 = *(const float4*)&w_s[kg * 24 + ct * 8 + 4];
                    const float* hp = &hs[kk * 68 + 8 * bt];
                    const float2 h01 = *(const float2*)(hp + 0);
                    const float2 h23 = *(const float2*)(hp + 2);
                    const float2 h45 = *(const float2*)(hp + 4);
                    const float2 h67 = *(const float2*)(hp + 6);
                    const float hv[8] = {h01.x, h01.y, h23.x, h23.y, h45.x, h45.y, h67.x, h67.y};
                    #pragma unroll
                    for (int i = 0; i < 8; ++i) {
                        acc[i][0].x = fmaf(hv[i], w0.x, acc[i][0].x);
                        acc[i][0].y = fmaf(hv[i], w0.y, acc[i][0].y);
                        acc[i][0].z = fmaf(hv[i], w0.z, acc[i][0].z);
                        acc[i][0].w = fmaf(hv[i], w0.w, acc[i][0].w);
                        acc[i][1].x = fmaf(hv[i], w1.x, acc[i][1].x);
                        acc[i][1].y = fmaf(hv[i], w1.y, acc[i][1].y);
                        acc[i][1].z = fmaf(hv[i], w1.z, acc[i][1].z);
                        acc[i][1].w = fmaf(hv[i], w1.w, acc[i][1].w);
                    }
                }
            }
            // k-reduce within wave (ks bits 4,5 of lane)
            #pragma unroll
            for (int i = 0; i < 8; ++i)
                #pragma unroll
                for (int p = 0; p < 2; ++p) {
                    acc[i][p].x += __shfl_xor(acc[i][p].x, 16);
                    acc[i][p].y += __shfl_xor(acc[i][p].y, 16);
                    acc[i][p].z += __shfl_xor(acc[i][p].z, 16);
                    acc[i][p].w += __shfl_xor(acc[i][p].w, 16);
                    acc[i][p].x += __shfl_xor(acc[i][p].x, 32);
                    acc[i][p].y += __shfl_xor(acc[i][p].y, 32);
                    acc[i][p].z += __shfl_xor(acc[i][p].z, 32);
                    acc[i][p].w += __shfl_xor(acc[i][p].w, 32);
                }
            __syncthreads();                       // hs reads done; part overlays hs
            if ((tid & 63) < 16) {                 // skew bt*8 breaks bank aliasing
                #pragma unroll
                for (int i = 0; i < 8; ++i) {
                    const int base = wv * 1088 + (8 * bt + i) * 16 + ct * 8 + bt * 8;
                    *(float4*)&part[base + 0] = acc[i][0];
                    *(float4*)&part[base + 4] = acc[i][1];
                }
            }
            __syncthreads();
        }

        // cross-wave reduce + xg: thread owns gates {tid, tid+512}; gate = b*16+c
        {
            float v0 = myxg0, v1 = myxg1;
            if (step > 0) {
                const int gA = tid, gB = tid + 512;
                const int iA = gA + 8 * (gA >> 7);
                const int iB = gB + 8 * (gB >> 7);
                #pragma unroll
                for (int w = 0; w < 8; ++w) {
                    v0 += part[w * 1088 + iA];
                    v1 += part[w * 1088 + iB];
                }
            }
            g_s[(tid & 15) * 65 + (tid >> 4)] = v0;
            {
                const int gB = tid + 512;
                g_s[(gB & 15) * 65 + (gB >> 4)] = v1;
            }
        }
        __syncthreads();

        if (tid < 256) {
            const int b = tid & 63, uu = tid >> 6;      // uu 0..3
            const float ig = sigm(g_s[(0  + uu) * 65 + b]);
            const float fg = sigm(g_s[(4  + uu) * 65 + b]);
            const float gg = tanhf(g_s[(8  + uu) * 65 + b]);
            const float og = sigm(g_s[(12 + uu) * 65 + b]);
            cst = fg * cst + ig * gg;
            hpub[tid] = og * tanhf(cst);           // [uu][b]
        }
        __syncthreads();
        if (tid < 16) {                            // coalesced publication (1 KB)
            const float4 v = *(const float4*)&hpub[tid * 16];
            coh_store4(v, Hbuf + (step & 1) * (512 * 64) + s * 256 + tid * 16);
            *(float4*)(out + (size_t)(col_off + 4 * s + (tid >> 2)) * NR
                           + (size_t)t * 64 + (tid & 3) * 16) = v;
        }
        if (wv == 0) wait_vm0();                   // h at coherent point
        __syncthreads();
        if (tid == 0)
            __hip_atomic_store(flag + step * NBLK + s, 1,
                               __ATOMIC_RELEASE, __HIP_MEMORY_SCOPE_AGENT);
    }
}

// ---------------------------------------------------------------------------
// BatchNorm stats over channel-major X2 [C2][NR]: block per channel
// ---------------------------------------------------------------------------
__global__ __launch_bounds__(256) void bn_stats(
    const float* __restrict__ X2, float* __restrict__ mean, float* __restrict__ istd)
{
    const int ch = blockIdx.x, tid = threadIdx.x;
    const float* base = X2 + (size_t)ch * NR;
    __shared__ float red[256];
    float s = 0.f;
    for (int i = tid * 4; i < NR; i += 1024) {
        const float4 v = *(const float4*)(base + i);
        s += v.x + v.y + v.z + v.w;
    }
    red[tid] = s; __syncthreads();
    for (int o = 128; o; o >>= 1) { if (tid < o) red[tid] += red[tid + o]; __syncthreads(); }
    const float mu = red[0] * (1.f / NR);
    __syncthreads();
    float vv = 0.f;
    for (int i = tid * 4; i < NR; i += 1024) {
        const float4 v = *(const float4*)(base + i);
        const float d0 = v.x - mu, d1 = v.y - mu, d2 = v.z - mu, d3 = v.w - mu;
        vv += d0 * d0 + d1 * d1 + d2 * d2 + d3 * d3;
    }
    red[tid] = vv; __syncthreads();
    for (int o = 128; o; o >>= 1) { if (tid < o) red[tid] += red[tid + o]; __syncthreads(); }
    if (tid == 0) { mean[ch] = mu; istd[ch] = rsqrtf(red[0] * (1.f / NR) + 1e-5f); }
}

// ---------------------------------------------------------------------------
// Fold BN into linear
// ---------------------------------------------------------------------------
__global__ void fold_lin(const float* __restrict__ lin_w, const float* __restrict__ lin_b,
                         const float* __restrict__ gamma, const float* __restrict__ beta,
                         const float* __restrict__ mean, const float* __restrict__ istd,
                         float* __restrict__ Wf, float* __restrict__ ct)
{
    const int t = blockIdx.x, tid = threadIdx.x;
    __shared__ float red[256];
    float acc = 0.f;
    for (int cc = tid; cc < C2; cc += 256) {
        const float w = lin_w[t * C2 + cc];
        const float g = gamma[cc] * istd[cc];
        Wf[t * C2 + cc] = w * g;
        acc = fmaf(beta[cc] - mean[cc] * g, w, acc);
    }
    red[tid] = acc; __syncthreads();
    for (int o = 128; o; o >>= 1) { if (tid < o) red[tid] += red[tid + o]; __syncthreads(); }
    if (tid == 0) ct[t] = red[0] + lin_b[t];
}

// ---------------------------------------------------------------------------
// Emission logits from channel-major X2: block per timestep t, lane = batch.
// ---------------------------------------------------------------------------
__global__ __launch_bounds__(256) void emit_logits(
    const float* __restrict__ X2, const float* __restrict__ Wf,
    const float* __restrict__ ct, float* __restrict__ E)
{
    __shared__ float ps[256 * TT];               // 17408 B partials
    const int t = blockIdx.x;
    const int tid = threadIdx.x;
    const int b = tid & 63, p = tid >> 6;
    const float* xb = X2 + (size_t)t * 64 + b;

    float acc[TT];
    #pragma unroll
    for (int k = 0; k < TT; k++) acc[k] = 0.f;

    for (int c0 = p * 256; c0 < p * 256 + 256; c0 += 4) {
        const float x0 = xb[(size_t)(c0 + 0) * NR];
        const float x1 = xb[(size_t)(c0 + 1) * NR];
        const float x2 = xb[(size_t)(c0 + 2) * NR];
        const float x3 = xb[(size_t)(c0 + 3) * NR];
        #pragma unroll
        for (int k = 0; k < TT; k++) {
            const float4 w = *(const float4*)&Wf[k * C2 + c0];   // wave-uniform
            acc[k] = fmaf(x0, w.x, fmaf(x1, w.y, fmaf(x2, w.z, fmaf(x3, w.w, acc[k]))));
        }
    }
    #pragma unroll
    for (int k = 0; k < TT; k++) ps[tid * TT + k] = acc[k];
    __syncthreads();
    if (tid < 64) {
        float* Er = E + ((size_t)tid * SL + t) * TT;
        #pragma unroll
        for (int k = 0; k < TT; k++) {
            float v = ct[k];
            #pragma unroll
            for (int q = 0; q < 4; q++) v += ps[(q * 64 + tid) * TT + k];
            Er[k] = v;
        }
    }
}

// ---------------------------------------------------------------------------
// CRF log-likelihood per batch element
// ---------------------------------------------------------------------------
__global__ __launch_bounds__(64) void crf_llh(
    const float* __restrict__ E, const int* __restrict__ mask,
    const int* __restrict__ labels, const float* __restrict__ startv,
    const float* __restrict__ endv, const float* __restrict__ trans,
    float* __restrict__ res)
{
    const int b = blockIdx.x, lane = threadIdx.x;
    __shared__ float tr[TT][TT];
    for (int i = lane; i < TT * TT; i += 64) tr[i / TT][i % TT] = trans[i];
    __syncthreads();
    const float* Eb = E + (size_t)b * SL * TT;
    const int j = (lane < TT) ? lane : 0;

    float alpha = -1e30f;
    if (lane < TT) alpha = startv[lane] + Eb[lane];

    float numacc = 0.f; int len = 0;
    for (int t = lane; t < SL; t += 64) {
        const int mt = mask[t * BS + b];
        len += (mt != 0);
        if (t >= 1 && mt) {
            const int yp = labels[(t - 1) * BS + b];
            const int yt = labels[t * BS + b];
            numacc += tr[yp][yt] + Eb[t * TT + yt];
        }
    }
    for (int off = 32; off; off >>= 1) {
        numacc += __shfl_xor(numacc, off);
        len += __shfl_xor(len, off);
    }

    for (int t = 1; t < SL; ++t) {
        const int mt = mask[t * BS + b];
        if (mt) {
            float av[TT];
            #pragma unroll
            for (int i = 0; i < TT; i++) av[i] = __shfl(alpha, i);
            const float e = (lane < TT) ? Eb[t * TT + lane] : 0.f;
            float mx = -1e30f;
            #pragma unroll
            for (int i = 0; i < TT; i++) mx = fmaxf(mx, av[i] + tr[i][j]);
            float ssum = 0.f;
            #pragma unroll
            for (int i = 0; i < TT; i++) ssum += expf(av[i] + tr[i][j] - mx);
            const float nxt = mx + logf(ssum) + e;
            if (lane < TT) alpha = nxt;
        }
    }
    float v = (lane < TT) ? alpha + endv[lane] : -1e30f;
    float mx = v;
    for (int off = 32; off; off >>= 1) mx = fmaxf(mx, __shfl_xor(mx, off));
    float se = (lane < TT) ? expf(v - mx) : 0.f;
    for (int off = 32; off; off >>= 1) se += __shfl_xor(se, off);
    const float Z = mx + logf(se);

    if (lane == 0) {
        const int y0 = labels[b];
        float num = startv[y0] + Eb[y0] + numacc;
        const int last = len - 1;
        const int yl = labels[last * BS + b];
        num += endv[yl];
        res[b] = num - Z;
    }
}

__global__ __launch_bounds__(64) void loss_reduce(const float* __restrict__ res, float* __restrict__ out)
{
    const int lane = threadIdx.x;
    float v = res[lane];
    for (int off = 32; off; off >>= 1) v += __shfl_xor(v, off);
    if (lane == 0) out[0] = -v;
}

// ---------------------------------------------------------------------------
// Viterbi per batch element
// ---------------------------------------------------------------------------
__global__ __launch_bounds__(64) void viterbi(
    const float* __restrict__ E, const int* __restrict__ mask,
    const float* __restrict__ startv, const float* __restrict__ endv,
    const float* __restrict__ trans, float* __restrict__ preds)
{
    const int b = blockIdx.x, lane = threadIdx.x;
    __shared__ float tr[TT][TT];
    __shared__ unsigned char bp[SL][TT];
    for (int i = lane; i < TT * TT; i += 64) tr[i / TT][i % TT] = trans[i];
    __syncthreads();
    const float* Eb = E + (size_t)b * SL * TT;
    const int j = (lane < TT) ? lane : 0;

    float score = (lane < TT) ? startv[lane] + Eb[lane] : -1e30f;
    for (int t = 1; t < SL; ++t) {
        float av[TT];
        #pragma unroll
        for (int i = 0; i < TT; i++) av[i] = __shfl(score, i);
        float best = -1e30f; int bi = 0;
        #pragma unroll
        for (int i = 0; i < TT; i++) {
            const float cand = av[i] + tr[i][j];
            if (cand > best) { best = cand; bi = i; }   // strict > => first max
        }
        const int mt = mask[t * BS + b];
        if (lane < TT) {
            bp[t][lane] = (unsigned char)bi;
            if (mt) score = best + Eb[t * TT + lane];
        }
    }
    float v = (lane < TT) ? score + endv[lane] : -1e30f;
    float mx = v;
    for (int off = 32; off; off >>= 1) mx = fmaxf(mx, __shfl_xor(mx, off));
    unsigned long long ball = __ballot(v == mx);
    const int last_tag = __ffsll(ball) - 1;
    __syncthreads();

    if (lane == 0) {
        int tag = last_tag;
        float* pb = preds + (size_t)b * SL;
        for (int t = SL - 1; t >= 1; --t) {
            const int mt = mask[t * BS + b];
            pb[t] = mt ? (float)tag : 0.f;
            if (mt) tag = bp[t][tag];
        }
        pb[0] = mask[b] ? (float)tag : 0.f;
    }
}

// ---------------------------------------------------------------------------
extern "C" void kernel_launch(void* const* d_in, const int* in_sizes, int n_in,
                              void* d_out, int out_size, void* d_ws, size_t ws_size,
                              hipStream_t stream)
{
    const float* word    = (const float*)d_in[0];
    const int*   mask    = (const int*)  d_in[1];
    const int*   labels  = (const int*)  d_in[2];
    const float* w_ih_f  = (const float*)d_in[3];
    const float* w_hh_f  = (const float*)d_in[4];
    const float* b_ih_f  = (const float*)d_in[5];
    const float* b_hh_f  = (const float*)d_in[6];
    const float* w_ih_b  = (const float*)d_in[7];
    const float* w_hh_b  = (const float*)d_in[8];
    const float* b_ih_b  = (const float*)d_in[9];
    const float* b_hh_b  = (const float*)d_in[10];
    const float* gamma   = (const float*)d_in[11];
    const float* beta    = (const float*)d_in[12];
    const float* lin_w   = (const float*)d_in[13];
    const float* lin_b   = (const float*)d_in[14];
    const float* c_start = (const float*)d_in[15];
    const float* c_end   = (const float*)d_in[16];
    const float* c_trans = (const float*)d_in[17];
    float* out = (float*)d_out;
    (void)in_sizes; (void)n_in; (void)out_size;

    char* ws = (char*)d_ws;
    size_t off = 0;
    auto alloc = [&](size_t bytes) {
        void* p = ws + off;
        off += (bytes + 255) & ~(size_t)255;
        return p;
    };
    // Layout byte-identical to the round-2 verified version (~335 MB merged).
    float* XG_F  = (float*)alloc((size_t)NR * G4 * 4);          // 128 MB
    float* WPK_F = (float*)alloc((size_t)128 * 12288 * 4);      // 6.3 MB
    float* WPK_B = (float*)alloc((size_t)128 * 12288 * 4);      // 6.3 MB
    float* LOUT  = (float*)alloc((size_t)NR * C2 * 4);          // 64 MB channel-major
    float* HB_F  = (float*)alloc((size_t)2 * 512 * 64 * 4);     // 256 KB
    float* HB_B  = (float*)alloc((size_t)2 * 512 * 64 * 4);     // 256 KB
    int*   FLAGS = (int*)  alloc((size_t)2 * SL * NBLK * 4);    // 256 KB
    float* MEAN  = (float*)alloc(C2 * 4);
    float* ISTD  = (float*)alloc(C2 * 4);
    float* WF    = (float*)alloc(TT * C2 * 4);
    float* CT    = (float*)alloc(TT * 4);
    float* Ebuf  = (float*)alloc((size_t)BS * SL * TT * 4);
    float* RES   = (float*)alloc(BS * 4);
    float* XG_B  = (float*)alloc((size_t)NR * G4 * 4);          // 128 MB (merged only)
    const bool merged = (ws_size >= off);                       // ~336 MB needed
    if (!merged) XG_B = XG_F;                                   // sequential reuse

    init_flags<<<128, 512, 0, stream>>>(FLAGS);
    pack_whh_v3<<<128, 256, 0, stream>>>(w_hh_f, WPK_F);
    pack_whh_v3<<<128, 256, 0, stream>>>(w_hh_b, WPK_B);

    if (merged) {
        gemm_xg_mfma<<<dim3(G4 / 128, NR / 128), 256, 0, stream>>>(word, w_ih_f, b_ih_f, b_hh_f, XG_F);
        gemm_xg_mfma<<<dim3(G4 / 128, NR / 128), 256, 0, stream>>>(word, w_ih_b, b_ih_b, b_hh_b, XG_B);
        lstm_flag<<<2 * NBLK, 512, 0, stream>>>(XG_F, XG_B, WPK_F, WPK_B, HB_F, HB_B,
                                                FLAGS, FLAGS + SL * NBLK, LOUT, 0);
    } else {
        gemm_xg_mfma<<<dim3(G4 / 128, NR / 128), 256, 0, stream>>>(word, w_ih_f, b_ih_f, b_hh_f, XG_F);
        lstm_flag<<<NBLK, 512, 0, stream>>>(XG_F, XG_B, WPK_F, WPK_B, HB_F, HB_B,
                                            FLAGS, FLAGS + SL * NBLK, LOUT, 0);
        gemm_xg_mfma<<<dim3(G4 / 128, NR / 128), 256, 0, stream>>>(word, w_ih_b, b_ih_b, b_hh_b, XG_F);
        lstm_flag<<<NBLK, 512, 0, stream>>>(XG_F, XG_B, WPK_F, WPK_B, HB_F, HB_B,
                                            FLAGS, FLAGS + SL * NBLK, LOUT, 1);
    }

    bn_stats<<<C2, 256, 0, stream>>>(LOUT, MEAN, ISTD);
    fold_lin<<<TT, 256, 0, stream>>>(lin_w, lin_b, gamma, beta, MEAN, ISTD, WF, CT);
    emit_logits<<<SL, 256, 0, stream>>>(LOUT, WF, CT, Ebuf);

    crf_llh<<<BS, 64, 0, stream>>>(Ebuf, mask, labels, c_start, c_end, c_trans, RES);
    loss_reduce<<<1, 64, 0, stream>>>(RES, out);
    viterbi<<<BS, 64, 0, stream>>>(Ebuf, mask, c_start, c_end, c_trans, out + 1);
}

// Round 9
// 8168.228 us; speedup vs baseline: 1.3312x; 1.0727x over previous
//
#include <hip/hip_runtime.h>
#include <hip/hip_bf16.h>
#include <math.h>

// Problem constants
#define SL 256
#define BS 64
#define DI 1024
#define HH 512
#define TT 17
#define NR (SL*BS)        // 16384 rows
#define G4 (4*HH)         // 2048 gates
#define C2 (2*HH)         // 1024 channels
#define NBLK 128          // blocks per direction in lstm_flag (4 h-units each)

__device__ __forceinline__ float sigm(float x) { return 1.f / (1.f + expf(-x)); }

typedef float vfloat4 __attribute__((ext_vector_type(4)));
typedef __attribute__((ext_vector_type(8))) short short8v;   // 8 bf16 (4 VGPRs)
typedef __attribute__((ext_vector_type(4))) float f32x4;     // MFMA acc

// Coherent (L1/L2-bypassing, agent-visible) 16B accesses for the LSTM h
// exchange. Loads valid after wait_vm0(); stores visible after wait_vm0().
__device__ __forceinline__ void coh_load4(float4& d, const float* p) {
    asm volatile("global_load_dwordx4 %0, %1, off sc0 sc1" : "=v"(d) : "v"(p) : "memory");
}
__device__ __forceinline__ void coh_load4i(int4& d, const int* p) {
    asm volatile("global_load_dwordx4 %0, %1, off sc0 sc1" : "=v"(d) : "v"(p) : "memory");
}
__device__ __forceinline__ void coh_store4(const float4& d, float* p) {
    vfloat4 t; t.x = d.x; t.y = d.y; t.z = d.z; t.w = d.w;
    asm volatile("global_store_dwordx4 %0, %1, off sc0 sc1" :: "v"(p), "v"(t) : "memory");
}
__device__ __forceinline__ void wait_vm0() { asm volatile("s_waitcnt vmcnt(0)" ::: "memory"); }

// fp32 -> bf16 hi (truncate) + bf16 lo (rne of residual); x ~ hi + lo to
// ~2^-17 relative. Dropped lo*lo MFMA term is 2^-18/term (round-7 verified).
__device__ __forceinline__ void split4(const float4& x, ushort4& h, ushort4& l)
{
    const float xs[4] = {x.x, x.y, x.z, x.w};
    ushort hh[4], ll[4];
    #pragma unroll
    for (int j = 0; j < 4; ++j) {
        const uint u   = __float_as_uint(xs[j]);
        const float hf = __uint_as_float(u & 0xFFFF0000u);
        hh[j] = (ushort)(u >> 16);
        const float lo = xs[j] - hf;
        const uint v   = __float_as_uint(lo);
        ll[j] = (ushort)((v + 0x7FFFu + ((v >> 16) & 1u)) >> 16);
    }
    h.x = hh[0]; h.y = hh[1]; h.z = hh[2]; h.w = hh[3];
    l.x = ll[0]; l.y = ll[1]; l.z = ll[2]; l.w = ll[3];
}

// ---------------------------------------------------------------------------
// Canonical LDS-staged MFMA split-bf16 GEMM: C = X @ W^T + b1 + b2, written
// slice-major XG2[((s*SL+t)*BS+b)*16 + c].
// n-tile is GATE-GROUPED: block (bx,by) covers units u0=bx*32..u0+31 across
// ALL 4 gates (n = g*512 + u0 + du, n_local = g*32+du) so it owns entire
// 4KB slice-major chunks -> fully coalesced epilogue (round-8's 4B scatter
// was ~64-transaction store insts + 4x RMW amplification).
// Load side: coalesced float4 staging (dense 64B lines, no inter-wave
// duplication), in-register hi/lo split, bf16 LDS tiles [128][40] (pad ->
// 16B-aligned conflict-free-ish b128 frag reads), register prefetch of
// tile kt+1 during MFMA. 3 passes (hh+hl+lh), fp32 accum.
// 128x128 tile, 4 waves (2x2), wave = 64x64 = 4x4 16x16x32 frags.
// Layouts (round-7 verified): A row=lane&15, k=(lane>>4)*8+j; B col same;
// D col=lane&15, row=(lane>>4)*4+reg.
// ---------------------------------------------------------------------------
__global__ __launch_bounds__(256) void gemm_xg_v2(
    const float* __restrict__ A,    // [NR][DI] fp32
    const float* __restrict__ W,    // [G4][DI] fp32
    const float* __restrict__ b1,
    const float* __restrict__ b2,
    float* __restrict__ C)
{
    __shared__ ushort smem[4 * 128 * 40];        // 40960 B
    ushort* const Ah = smem;                     // [128][40]
    ushort* const Al = smem + 1 * 5120;
    ushort* const Bh = smem + 2 * 5120;
    ushort* const Bl = smem + 3 * 5120;

    const int tid  = threadIdx.x;
    const int lane = tid & 63;
    const int w    = tid >> 6;
    const int wm   = w >> 1, wn = w & 1;
    const int bx   = blockIdx.x;                 // u-tile (fast -> A-panel L2 reuse)
    const int by   = blockIdx.y;                 // m-tile
    const int m0   = by * 128;
    const int u0   = bx * 32;
    const int lr   = lane & 15;
    const int lk   = (lane >> 4) * 8;

    // bias per j (n mapping: n_local = wn*64+j*16+lr -> g=nl>>5, du=nl&31)
    float bs[4];
    #pragma unroll
    for (int j = 0; j < 4; ++j) {
        const int nl = wn * 64 + j * 16 + lr;
        const int n  = (nl >> 5) * 512 + u0 + (nl & 31);
        bs[j] = b1[n] + b2[n];
    }

    // staging descriptors: thread handles float4 idx f = tid + p*256
    int arow[4], acol[4], brow[4];
    #pragma unroll
    for (int p = 0; p < 4; ++p) {
        const int f = tid + p * 256;
        arow[p] = f >> 3;                        // 0..127
        acol[p] = (f & 7) * 4;                   // 0..28
        brow[p] = (arow[p] >> 5) * 512 + u0 + (arow[p] & 31);   // W row
    }

    f32x4 acc[4][4];
    #pragma unroll
    for (int i = 0; i < 4; i++)
        #pragma unroll
        for (int j = 0; j < 4; j++) {
            acc[i][j][0] = 0.f; acc[i][j][1] = 0.f;
            acc[i][j][2] = 0.f; acc[i][j][3] = 0.f;
        }

    float4 ra[4], rb[4];
    #pragma unroll
    for (int p = 0; p < 4; ++p) {               // prologue: tile 0
        ra[p] = *(const float4*)(A + (size_t)(m0 + arow[p]) * DI + acol[p]);
        rb[p] = *(const float4*)(W + (size_t)brow[p] * DI + acol[p]);
    }

    for (int kt = 0; kt < DI; kt += 32) {
        if (kt) __syncthreads();                // prev tile's frag reads done
        #pragma unroll
        for (int p = 0; p < 4; ++p) {           // split + LDS write (8B, aligned)
            ushort4 h, l;
            split4(ra[p], h, l);
            *(ushort4*)&Ah[arow[p] * 40 + acol[p]] = h;
            *(ushort4*)&Al[arow[p] * 40 + acol[p]] = l;
            split4(rb[p], h, l);
            *(ushort4*)&Bh[arow[p] * 40 + acol[p]] = h;
            *(ushort4*)&Bl[arow[p] * 40 + acol[p]] = l;
        }
        __syncthreads();                        // tile ready
        if (kt + 32 < DI) {                     // prefetch next tile (hidden)
            #pragma unroll
            for (int p = 0; p < 4; ++p) {
                ra[p] = *(const float4*)(A + (size_t)(m0 + arow[p]) * DI + kt + 32 + acol[p]);
                rb[p] = *(const float4*)(W + (size_t)brow[p] * DI + kt + 32 + acol[p]);
            }
        }
        short8v ah[4], al[4], bh[4], bl[4];
        #pragma unroll
        for (int i = 0; i < 4; ++i) {
            const int mr = wm * 64 + i * 16 + lr;
            const int nr = wn * 64 + i * 16 + lr;
            ah[i] = *(const short8v*)&Ah[mr * 40 + lk];
            al[i] = *(const short8v*)&Al[mr * 40 + lk];
            bh[i] = *(const short8v*)&Bh[nr * 40 + lk];
            bl[i] = *(const short8v*)&Bl[nr * 40 + lk];
        }
        #pragma unroll
        for (int i = 0; i < 4; i++)
            #pragma unroll
            for (int j = 0; j < 4; j++)
                acc[i][j] = __builtin_amdgcn_mfma_f32_16x16x32_bf16(ah[i], bh[j], acc[i][j], 0, 0, 0);
        #pragma unroll
        for (int i = 0; i < 4; i++)
            #pragma unroll
            for (int j = 0; j < 4; j++)
                acc[i][j] = __builtin_amdgcn_mfma_f32_16x16x32_bf16(ah[i], bl[j], acc[i][j], 0, 0, 0);
        #pragma unroll
        for (int i = 0; i < 4; i++)
            #pragma unroll
            for (int j = 0; j < 4; j++)
                acc[i][j] = __builtin_amdgcn_mfma_f32_16x16x32_bf16(al[i], bh[j], acc[i][j], 0, 0, 0);
    }

    // epilogue: stage C through LDS in 2 m-halves, write coalesced 4KB chunks
    __syncthreads();                            // LDS free for reuse
    float* const Cl = (float*)smem;             // 8192 floats = 32KB of 40KB
    const size_t s_base = (size_t)bx * 8;       // u0>>2
    #pragma unroll
    for (int h = 0; h < 2; ++h) {
        if (h) __syncthreads();                 // prev half fully written out
        if (wm == h) {
            #pragma unroll
            for (int i = 0; i < 4; ++i)
                #pragma unroll
                for (int j = 0; j < 4; ++j) {
                    const int nl = wn * 64 + j * 16 + lr;
                    const int g = nl >> 5, du = nl & 31;
                    const int s_rel = du >> 2, c = g * 4 + (du & 3);
                    #pragma unroll
                    for (int r = 0; r < 4; ++r) {
                        const int ml = i * 16 + (lane >> 4) * 4 + r;   // 0..63
                        Cl[s_rel * 1024 + ml * 16 + c] = acc[i][j][r] + bs[j];
                    }
                }
        }
        __syncthreads();                        // Cl ready
        const int mt_g = by * 2 + h;
        #pragma unroll
        for (int ch = 0; ch < 8; ++ch) {
            const float4 v = *(const float4*)&Cl[ch * 1024 + tid * 4];
            *(float4*)(C + ((s_base + ch) * SL + mt_g) * 1024 + tid * 4) = v;
        }
    }
}

// ---------------------------------------------------------------------------
// Pack w_hh (2048x512) -> wp[128 slices][512 k][24] (cols c=g*4+uu, pad 16..23)
// ---------------------------------------------------------------------------
__global__ __launch_bounds__(256) void pack_whh_v3(const float* __restrict__ whh,
                                                   float* __restrict__ wp)
{
    const int s = blockIdx.x;
    for (int idx = threadIdx.x; idx < 512 * 24; idx += 256) {
        const int k = idx / 24, c = idx % 24;
        float v = 0.f;
        if (c < 16) {
            const int g = c >> 2, uu = c & 3;
            v = whh[(size_t)(g * 512 + 4 * s + uu) * HH + k];
        }
        wp[(size_t)s * 12288 + idx] = v;
    }
}

__global__ __launch_bounds__(512) void init_flags(int* __restrict__ f)
{
    f[blockIdx.x * 512 + threadIdx.x] = 0;   // 128*512 = 2*SL*NBLK ints
}

// ---------------------------------------------------------------------------
// Flag-pipelined LSTM (round-2 verified version, 3.6 ms). Grid 256 merged
// (1 block/CU) or 128. Block s owns h-units {4s..4s+3}. Weights LDS-resident.
// Poll prev flags (uncached int4) -> stage H(t-1) in 4 chunks of coherent
// dwordx4 (next chunk prefetched during compute) -> GEMM -> shfl k-reduce ->
// skewed LDS cross-wave reduce -> gates (c in regs) -> publish + flag.
// ---------------------------------------------------------------------------
__global__ __launch_bounds__(512, 2) void lstm_flag(
    const float* __restrict__ xg_f, const float* __restrict__ xg_b,  // slice-major
    const float* __restrict__ wp_f, const float* __restrict__ wp_b,
    float* __restrict__ Hf, float* __restrict__ Hb,
    int* __restrict__ flag_f, int* __restrict__ flag_b,
    float* __restrict__ out,          // channel-major [C2][NR]
    int dir_base)
{
    __shared__ float w_s[512 * 24];              // 49152 B, persistent
    __shared__ float hs[128 * 68];               // 34816 B, reused per chunk
    __shared__ float g_s[16 * 65];               //  4160 B
    __shared__ float hpub[256];                  //  1024 B
    float* const part = hs;                      // [8][1088] overlay (exact fit)

    const int dir = dir_base + (blockIdx.x >> 7);
    const int s   = blockIdx.x & 127;
    const float* xg  = dir ? xg_b : xg_f;
    const float* wp  = dir ? wp_b : wp_f;
    float* Hbuf      = dir ? Hb : Hf;
    int*   flag      = dir ? flag_b : flag_f;
    const int reverse = dir;
    const int col_off = dir * HH;

    const int tid = threadIdx.x;
    const int ks  = tid >> 4;        // 0..31 k-slice
    const int bt  = (tid >> 1) & 7;  // 0..7 batch tile
    const int ct  = tid & 1;         // 0..1 col tile (8 cols each)
    const int wv  = tid >> 6;        // wave 0..7

    // stage weights once (3072 float4)
    {
        const float4* src = (const float4*)(wp + (size_t)s * 12288);
        float4* dst = (float4*)w_s;
        for (int i = tid; i < 3072; i += 512) dst[i] = src[i];
    }

    const float* xgs = xg + (size_t)s * (SL * 1024);
    float cst = 0.f;                  // c-state: tid<256 owns (b=tid&63, uu=tid>>6)
    float4 r[4];
    float4 acc[8][2];

    for (int step = 0; step < SL; ++step) {
        const int t = reverse ? (SL - 1 - step) : step;
        const float myxg0 = xgs[t * 1024 + tid];
        const float myxg1 = xgs[t * 1024 + 512 + tid];

        if (step > 0) {
            if (tid < 32) {
                const int* fp = flag + (step - 1) * NBLK + tid * 4;
                int4 f;
                for (;;) {
                    coh_load4i(f, fp);
                    wait_vm0();
                    if (f.x & f.y & f.z & f.w) break;
                    __builtin_amdgcn_s_sleep(1);
                }
            }
            __syncthreads();   // flags seen; also protects w_s/hs reuse

            const float* hsrc = Hbuf + ((step + 1) & 1) * (512 * 64);
            #pragma unroll
            for (int i = 0; i < 4; ++i)
                coh_load4(r[i], hsrc + (size_t)(i * 512 + tid) * 4);

            #pragma unroll
            for (int i = 0; i < 8; ++i) {
                acc[i][0] = make_float4(0.f, 0.f, 0.f, 0.f);
                acc[i][1] = make_float4(0.f, 0.f, 0.f, 0.f);
            }

            for (int kc = 0; kc < 4; ++kc) {
                if (kc) __syncthreads();           // prev chunk consumed
                wait_vm0();
                #pragma unroll
                for (int i = 0; i < 4; ++i) {
                    const int idx = i * 512 + tid;        // float4 index in chunk
                    const int k = idx >> 4, b4 = (idx & 15) * 4;
                    *(float4*)&hs[k * 68 + b4] = r[i];
                }
                __syncthreads();                   // hs ready
                if (kc < 3) {                      // prefetch next chunk during compute
                    const float* base = hsrc + (size_t)(kc + 1) * 8192;
                    #pragma unroll
                    for (int i = 0; i < 4; ++i)
                        coh_load4(r[i], base + (size_t)(i * 512 + tid) * 4);
                }
                #pragma unroll
                for (int j = 0; j < 4; ++j) {
                    const int kk = ks + 32 * j;
                    const int kg = kc * 128 + kk;
                    const float4 w0 = *(const float4*)&w_s[kg * 24 + ct * 8];
                    const float4 w1 = *(const float4*)&w_s[kg * 24 + ct * 8 + 4];
                    const float* hp = &hs[kk * 68 + 8 * bt];
                    const float2 h01 = *(const float2*)(hp + 0);
                    const float2 h23 = *(const float2*)(hp + 2);
                    const float2 h45 = *(const float2*)(hp + 4);
                    const float2 h67 = *(const float2*)(hp + 6);
                    const float hv[8] = {h01.x, h01.y, h23.x, h23.y, h45.x, h45.y, h67.x, h67.y};
                    #pragma unroll
                    for (int i = 0; i < 8; ++i) {
                        acc[i][0].x = fmaf(hv[i], w0.x, acc[i][0].x);
                        acc[i][0].y = fmaf(hv[i], w0.y, acc[i][0].y);
                        acc[i][0].z = fmaf(hv[i], w0.z, acc[i][0].z);
                        acc[i][0].w = fmaf(hv[i], w0.w, acc[i][0].w);
                        acc[i][1].x = fmaf(hv[i], w1.x, acc[i][1].x);
                        acc[i][1].y = fmaf(hv[i], w1.y, acc[i][1].y);
                        acc[i][1].z = fmaf(hv[i], w1.z, acc[i][1].z);
                        acc[i][1].w = fmaf(hv[i], w1.w, acc[i][1].w);
                    }
                }
            }
            // k-reduce within wave (ks bits 4,5 of lane)
            #pragma unroll
            for (int i = 0; i < 8; ++i)
                #pragma unroll
                for (int p = 0; p < 2; ++p) {
                    acc[i][p].x += __shfl_xor(acc[i][p].x, 16);
                    acc[i][p].y += __shfl_xor(acc[i][p].y, 16);
                    acc[i][p].z += __shfl_xor(acc[i][p].z, 16);
                    acc[i][p].w += __shfl_xor(acc[i][p].w, 16);
                    acc[i][p].x += __shfl_xor(acc[i][p].x, 32);
                    acc[i][p].y += __shfl_xor(acc[i][p].y, 32);
                    acc[i][p].z += __shfl_xor(acc[i][p].z, 32);
                    acc[i][p].w += __shfl_xor(acc[i][p].w, 32);
                }
            __syncthreads();                       // hs reads done; part overlays hs
            if ((tid & 63) < 16) {                 // skew bt*8 breaks bank aliasing
                #pragma unroll
                for (int i = 0; i < 8; ++i) {
                    const int base = wv * 1088 + (8 * bt + i) * 16 + ct * 8 + bt * 8;
                    *(float4*)&part[base + 0] = acc[i][0];
                    *(float4*)&part[base + 4] = acc[i][1];
                }
            }
            __syncthreads();
        }

        // cross-wave reduce + xg: thread owns gates {tid, tid+512}; gate = b*16+c
        {
            float v0 = myxg0, v1 = myxg1;
            if (step > 0) {
                const int gA = tid, gB = tid + 512;
                const int iA = gA + 8 * (gA >> 7);
                const int iB = gB + 8 * (gB >> 7);
                #pragma unroll
                for (int w = 0; w < 8; ++w) {
                    v0 += part[w * 1088 + iA];
                    v1 += part[w * 1088 + iB];
                }
            }
            g_s[(tid & 15) * 65 + (tid >> 4)] = v0;
            {
                const int gB = tid + 512;
                g_s[(gB & 15) * 65 + (gB >> 4)] = v1;
            }
        }
        __syncthreads();

        if (tid < 256) {
            const int b = tid & 63, uu = tid >> 6;      // uu 0..3
            const float ig = sigm(g_s[(0  + uu) * 65 + b]);
            const float fg = sigm(g_s[(4  + uu) * 65 + b]);
            const float gg = tanhf(g_s[(8  + uu) * 65 + b]);
            const float og = sigm(g_s[(12 + uu) * 65 + b]);
            cst = fg * cst + ig * gg;
            hpub[tid] = og * tanhf(cst);           // [uu][b]
        }
        __syncthreads();
        if (tid < 16) {                            // coalesced publication (1 KB)
            const float4 v = *(const float4*)&hpub[tid * 16];
            coh_store4(v, Hbuf + (step & 1) * (512 * 64) + s * 256 + tid * 16);
            *(float4*)(out + (size_t)(col_off + 4 * s + (tid >> 2)) * NR
                           + (size_t)t * 64 + (tid & 3) * 16) = v;
        }
        if (wv == 0) wait_vm0();                   // h at coherent point
        __syncthreads();
        if (tid == 0)
            __hip_atomic_store(flag + step * NBLK + s, 1,
                               __ATOMIC_RELEASE, __HIP_MEMORY_SCOPE_AGENT);
    }
}

// ---------------------------------------------------------------------------
// BatchNorm stats over channel-major X2 [C2][NR]: block per channel
// ---------------------------------------------------------------------------
__global__ __launch_bounds__(256) void bn_stats(
    const float* __restrict__ X2, float* __restrict__ mean, float* __restrict__ istd)
{
    const int ch = blockIdx.x, tid = threadIdx.x;
    const float* base = X2 + (size_t)ch * NR;
    __shared__ float red[256];
    float s = 0.f;
    for (int i = tid * 4; i < NR; i += 1024) {
        const float4 v = *(const float4*)(base + i);
        s += v.x + v.y + v.z + v.w;
    }
    red[tid] = s; __syncthreads();
    for (int o = 128; o; o >>= 1) { if (tid < o) red[tid] += red[tid + o]; __syncthreads(); }
    const float mu = red[0] * (1.f / NR);
    __syncthreads();
    float vv = 0.f;
    for (int i = tid * 4; i < NR; i += 1024) {
        const float4 v = *(const float4*)(base + i);
        const float d0 = v.x - mu, d1 = v.y - mu, d2 = v.z - mu, d3 = v.w - mu;
        vv += d0 * d0 + d1 * d1 + d2 * d2 + d3 * d3;
    }
    red[tid] = vv; __syncthreads();
    for (int o = 128; o; o >>= 1) { if (tid < o) red[tid] += red[tid + o]; __syncthreads(); }
    if (tid == 0) { mean[ch] = mu; istd[ch] = rsqrtf(red[0] * (1.f / NR) + 1e-5f); }
}

// ---------------------------------------------------------------------------
// Fold BN into linear
// ---------------------------------------------------------------------------
__global__ void fold_lin(const float* __restrict__ lin_w, const float* __restrict__ lin_b,
                         const float* __restrict__ gamma, const float* __restrict__ beta,
                         const float* __restrict__ mean, const float* __restrict__ istd,
                         float* __restrict__ Wf, float* __restrict__ ct)
{
    const int t = blockIdx.x, tid = threadIdx.x;
    __shared__ float red[256];
    float acc = 0.f;
    for (int cc = tid; cc < C2; cc += 256) {
        const float w = lin_w[t * C2 + cc];
        const float g = gamma[cc] * istd[cc];
        Wf[t * C2 + cc] = w * g;
        acc = fmaf(beta[cc] - mean[cc] * g, w, acc);
    }
    red[tid] = acc; __syncthreads();
    for (int o = 128; o; o >>= 1) { if (tid < o) red[tid] += red[tid + o]; __syncthreads(); }
    if (tid == 0) ct[t] = red[0] + lin_b[t];
}

// ---------------------------------------------------------------------------
// Emission logits from channel-major X2: block per timestep t, lane = batch.
// ---------------------------------------------------------------------------
__global__ __launch_bounds__(256) void emit_logits(
    const float* __restrict__ X2, const float* __restrict__ Wf,
    const float* __restrict__ ct, float* __restrict__ E)
{
    __shared__ float ps[256 * TT];               // 17408 B partials
    const int t = blockIdx.x;
    const int tid = threadIdx.x;
    const int b = tid & 63, p = tid >> 6;
    const float* xb = X2 + (size_t)t * 64 + b;

    float acc[TT];
    #pragma unroll
    for (int k = 0; k < TT; k++) acc[k] = 0.f;

    for (int c0 = p * 256; c0 < p * 256 + 256; c0 += 4) {
        const float x0 = xb[(size_t)(c0 + 0) * NR];
        const float x1 = xb[(size_t)(c0 + 1) * NR];
        const float x2 = xb[(size_t)(c0 + 2) * NR];
        const float x3 = xb[(size_t)(c0 + 3) * NR];
        #pragma unroll
        for (int k = 0; k < TT; k++) {
            const float4 w = *(const float4*)&Wf[k * C2 + c0];   // wave-uniform
            acc[k] = fmaf(x0, w.x, fmaf(x1, w.y, fmaf(x2, w.z, fmaf(x3, w.w, acc[k]))));
        }
    }
    #pragma unroll
    for (int k = 0; k < TT; k++) ps[tid * TT + k] = acc[k];
    __syncthreads();
    if (tid < 64) {
        float* Er = E + ((size_t)tid * SL + t) * TT;
        #pragma unroll
        for (int k = 0; k < TT; k++) {
            float v = ct[k];
            #pragma unroll
            for (int q = 0; q < 4; q++) v += ps[(q * 64 + tid) * TT + k];
            Er[k] = v;
        }
    }
}

// ---------------------------------------------------------------------------
// CRF log-likelihood per batch element
// ---------------------------------------------------------------------------
__global__ __launch_bounds__(64) void crf_llh(
    const float* __restrict__ E, const int* __restrict__ mask,
    const int* __restrict__ labels, const float* __restrict__ startv,
    const float* __restrict__ endv, const float* __restrict__ trans,
    float* __restrict__ res)
{
    const int b = blockIdx.x, lane = threadIdx.x;
    __shared__ float tr[TT][TT];
    for (int i = lane; i < TT * TT; i += 64) tr[i / TT][i % TT] = trans[i];
    __syncthreads();
    const float* Eb = E + (size_t)b * SL * TT;
    const int j = (lane < TT) ? lane : 0;

    float alpha = -1e30f;
    if (lane < TT) alpha = startv[lane] + Eb[lane];

    float numacc = 0.f; int len = 0;
    for (int t = lane; t < SL; t += 64) {
        const int mt = mask[t * BS + b];
        len += (mt != 0);
        if (t >= 1 && mt) {
            const int yp = labels[(t - 1) * BS + b];
            const int yt = labels[t * BS + b];
            numacc += tr[yp][yt] + Eb[t * TT + yt];
        }
    }
    for (int off = 32; off; off >>= 1) {
        numacc += __shfl_xor(numacc, off);
        len += __shfl_xor(len, off);
    }

    for (int t = 1; t < SL; ++t) {
        const int mt = mask[t * BS + b];
        if (mt) {
            float av[TT];
            #pragma unroll
            for (int i = 0; i < TT; i++) av[i] = __shfl(alpha, i);
            const float e = (lane < TT) ? Eb[t * TT + lane] : 0.f;
            float mx = -1e30f;
            #pragma unroll
            for (int i = 0; i < TT; i++) mx = fmaxf(mx, av[i] + tr[i][j]);
            float ssum = 0.f;
            #pragma unroll
            for (int i = 0; i < TT; i++) ssum += expf(av[i] + tr[i][j] - mx);
            const float nxt = mx + logf(ssum) + e;
            if (lane < TT) alpha = nxt;
        }
    }
    float v = (lane < TT) ? alpha + endv[lane] : -1e30f;
    float mx = v;
    for (int off = 32; off; off >>= 1) mx = fmaxf(mx, __shfl_xor(mx, off));
    float se = (lane < TT) ? expf(v - mx) : 0.f;
    for (int off = 32; off; off >>= 1) se += __shfl_xor(se, off);
    const float Z = mx + logf(se);

    if (lane == 0) {
        const int y0 = labels[b];
        float num = startv[y0] + Eb[y0] + numacc;
        const int last = len - 1;
        const int yl = labels[last * BS + b];
        num += endv[yl];
        res[b] = num - Z;
    }
}

__global__ __launch_bounds__(64) void loss_reduce(const float* __restrict__ res, float* __restrict__ out)
{
    const int lane = threadIdx.x;
    float v = res[lane];
    for (int off = 32; off; off >>= 1) v += __shfl_xor(v, off);
    if (lane == 0) out[0] = -v;
}

// ---------------------------------------------------------------------------
// Viterbi per batch element
// ---------------------------------------------------------------------------
__global__ __launch_bounds__(64) void viterbi(
    const float* __restrict__ E, const int* __restrict__ mask,
    const float* __restrict__ startv, const float* __restrict__ endv,
    const float* __restrict__ trans, float* __restrict__ preds)
{
    const int b = blockIdx.x, lane = threadIdx.x;
    __shared__ float tr[TT][TT];
    __shared__ unsigned char bp[SL][TT];
    for (int i = lane; i < TT * TT; i += 64) tr[i / TT][i % TT] = trans[i];
    __syncthreads();
    const float* Eb = E + (size_t)b * SL * TT;
    const int j = (lane < TT) ? lane : 0;

    float score = (lane < TT) ? startv[lane] + Eb[lane] : -1e30f;
    for (int t = 1; t < SL; ++t) {
        float av[TT];
        #pragma unroll
        for (int i = 0; i < TT; i++) av[i] = __shfl(score, i);
        float best = -1e30f; int bi = 0;
        #pragma unroll
        for (int i = 0; i < TT; i++) {
            const float cand = av[i] + tr[i][j];
            if (cand > best) { best = cand; bi = i; }   // strict > => first max
        }
        const int mt = mask[t * BS + b];
        if (lane < TT) {
            bp[t][lane] = (unsigned char)bi;
            if (mt) score = best + Eb[t * TT + lane];
        }
    }
    float v = (lane < TT) ? score + endv[lane] : -1e30f;
    float mx = v;
    for (int off = 32; off; off >>= 1) mx = fmaxf(mx, __shfl_xor(mx, off));
    unsigned long long ball = __ballot(v == mx);
    const int last_tag = __ffsll(ball) - 1;
    __syncthreads();

    if (lane == 0) {
        int tag = last_tag;
        float* pb = preds + (size_t)b * SL;
        for (int t = SL - 1; t >= 1; --t) {
            const int mt = mask[t * BS + b];
            pb[t] = mt ? (float)tag : 0.f;
            if (mt) tag = bp[t][tag];
        }
        pb[0] = mask[b] ? (float)tag : 0.f;
    }
}

// ---------------------------------------------------------------------------
extern "C" void kernel_launch(void* const* d_in, const int* in_sizes, int n_in,
                              void* d_out, int out_size, void* d_ws, size_t ws_size,
                              hipStream_t stream)
{
    const float* word    = (const float*)d_in[0];
    const int*   mask    = (const int*)  d_in[1];
    const int*   labels  = (const int*)  d_in[2];
    const float* w_ih_f  = (const float*)d_in[3];
    const float* w_hh_f  = (const float*)d_in[4];
    const float* b_ih_f  = (const float*)d_in[5];
    const float* b_hh_f  = (const float*)d_in[6];
    const float* w_ih_b  = (const float*)d_in[7];
    const float* w_hh_b  = (const float*)d_in[8];
    const float* b_ih_b  = (const float*)d_in[9];
    const float* b_hh_b  = (const float*)d_in[10];
    const float* gamma   = (const float*)d_in[11];
    const float* beta    = (const float*)d_in[12];
    const float* lin_w   = (const float*)d_in[13];
    const float* lin_b   = (const float*)d_in[14];
    const float* c_start = (const float*)d_in[15];
    const float* c_end   = (const float*)d_in[16];
    const float* c_trans = (const float*)d_in[17];
    float* out = (float*)d_out;
    (void)in_sizes; (void)n_in; (void)out_size;

    char* ws = (char*)d_ws;
    size_t off = 0;
    auto alloc = [&](size_t bytes) {
        void* p = ws + off;
        off += (bytes + 255) & ~(size_t)255;
        return p;
    };
    // Layout byte-identical to the round-2 verified version (~335 MB merged).
    float* XG_F  = (float*)alloc((size_t)NR * G4 * 4);          // 128 MB
    float* WPK_F = (float*)alloc((size_t)128 * 12288 * 4);      // 6.3 MB
    float* WPK_B = (float*)alloc((size_t)128 * 12288 * 4);      // 6.3 MB
    float* LOUT  = (float*)alloc((size_t)NR * C2 * 4);          // 64 MB channel-major
    float* HB_F  = (float*)alloc((size_t)2 * 512 * 64 * 4);     // 256 KB
    float* HB_B  = (float*)alloc((size_t)2 * 512 * 64 * 4);     // 256 KB
    int*   FLAGS = (int*)  alloc((size_t)2 * SL * NBLK * 4);    // 256 KB
    float* MEAN  = (float*)alloc(C2 * 4);
    float* ISTD  = (float*)alloc(C2 * 4);
    float* WF    = (float*)alloc(TT * C2 * 4);
    float* CT    = (float*)alloc(TT * 4);
    float* Ebuf  = (float*)alloc((size_t)BS * SL * TT * 4);
    float* RES   = (float*)alloc(BS * 4);
    float* XG_B  = (float*)alloc((size_t)NR * G4 * 4);          // 128 MB (merged only)
    const bool merged = (ws_size >= off);                       // ~336 MB needed
    if (!merged) XG_B = XG_F;                                   // sequential reuse

    init_flags<<<128, 512, 0, stream>>>(FLAGS);
    pack_whh_v3<<<128, 256, 0, stream>>>(w_hh_f, WPK_F);
    pack_whh_v3<<<128, 256, 0, stream>>>(w_hh_b, WPK_B);

    if (merged) {
        gemm_xg_v2<<<dim3(16, 128), 256, 0, stream>>>(word, w_ih_f, b_ih_f, b_hh_f, XG_F);
        gemm_xg_v2<<<dim3(16, 128), 256, 0, stream>>>(word, w_ih_b, b_ih_b, b_hh_b, XG_B);
        lstm_flag<<<2 * NBLK, 512, 0, stream>>>(XG_F, XG_B, WPK_F, WPK_B, HB_F, HB_B,
                                                FLAGS, FLAGS + SL * NBLK, LOUT, 0);
    } else {
        gemm_xg_v2<<<dim3(16, 128), 256, 0, stream>>>(word, w_ih_f, b_ih_f, b_hh_f, XG_F);
        lstm_flag<<<NBLK, 512, 0, stream>>>(XG_F, XG_B, WPK_F, WPK_B, HB_F, HB_B,
                                            FLAGS, FLAGS + SL * NBLK, LOUT, 0);
        gemm_xg_v2<<<dim3(16, 128), 256, 0, stream>>>(word, w_ih_b, b_ih_b, b_hh_b, XG_F);
        lstm_flag<<<NBLK, 512, 0, stream>>>(XG_F, XG_B, WPK_F, WPK_B, HB_F, HB_B,
                                            FLAGS, FLAGS + SL * NBLK, LOUT, 1);
    }

    bn_stats<<<C2, 256, 0, stream>>>(LOUT, MEAN, ISTD);
    fold_lin<<<TT, 256, 0, stream>>>(lin_w, lin_b, gamma, beta, MEAN, ISTD, WF, CT);
    emit_logits<<<SL, 256, 0, stream>>>(LOUT, WF, CT, Ebuf);

    crf_llh<<<BS, 64, 0, stream>>>(Ebuf, mask, labels, c_start, c_end, c_trans, RES);
    loss_reduce<<<1, 64, 0, stream>>>(RES, out);
    viterbi<<<BS, 64, 0, stream>>>(Ebuf, mask, c_start, c_end, c_trans, out + 1);
}